// Round 10
// baseline (586.451 us; speedup 1.0000x reference)
//
#include <hip/hip_runtime.h>

#define NCH    8
#define NBASIS 30
#define NXS    256
#define NF     200
#define NX     (NXS*NXS*2)      // 131072
#define NIMG   (NCH*NBASIS)     // 240

typedef float f32x2 __attribute__((ext_vector_type(2)));

__device__ __forceinline__ int bitrev8(int v) {
    return (int)(__builtin_bitreverse32((unsigned)v) >> 24);
}

// ---------------------------------------------------------------------------
// Pass 1: w = (x * csm) * (-1)^(row+col); FFT along the contiguous (col) axis.
// ---------------------------------------------------------------------------
__global__ __launch_bounds__(256) void fft_rows_kernel(
        const float* __restrict__ x, const float* __restrict__ csm,
        float* __restrict__ A) {
    __shared__ float ldsRe[4][256];
    __shared__ float ldsIm[4][256];
    __shared__ float twRe[128], twIm[128];

    const int tid   = threadIdx.x;
    const int slice = tid >> 6;
    const int lane  = tid & 63;
    const int blk   = blockIdx.x;       // m*64 + rowTile
    const int m     = blk >> 6;
    const int row   = ((blk & 63) << 2) + slice;
    const int c     = m / NBASIS;
    const int b     = m - c * NBASIS;

    if (tid < 128) {
        float a = (float)tid * (1.0f / 128.0f);   // theta = pi * a
        twRe[tid] =  cospif(a);
        twIm[tid] = -sinpif(a);
    }

    const float* xr = x   + ((size_t)(b * NXS + row) * NXS) * 2;
    const float* cr = csm + ((size_t)(c * NXS + row) * NXS) * 2;
    #pragma unroll
    for (int j = 0; j < 4; ++j) {
        int col = lane + 64 * j;
        float2 xv = *(const float2*)(xr + col * 2);
        float2 cv = *(const float2*)(cr + col * 2);
        float s = ((row + col) & 1) ? -1.0f : 1.0f;
        ldsRe[slice][col] = s * (xv.x * cv.x - xv.y * cv.y);
        ldsIm[slice][col] = s * (xv.x * cv.y + xv.y * cv.x);
    }
    __syncthreads();

    #pragma unroll
    for (int half = 128; half >= 1; half >>= 1) {
        #pragma unroll
        for (int qq = 0; qq < 2; ++qq) {
            int q  = lane + 64 * qq;
            int g  = q / half;
            int j  = q - g * half;
            int i0 = g * 2 * half + j;
            int i1 = i0 + half;
            float ar = ldsRe[slice][i0], ai = ldsIm[slice][i0];
            float br = ldsRe[slice][i1], bi = ldsIm[slice][i1];
            ldsRe[slice][i0] = ar + br;
            ldsIm[slice][i0] = ai + bi;
            float dr = ar - br, di = ai - bi;
            int k = j * (128 / half);
            float wr = twRe[k], wi = twIm[k];
            ldsRe[slice][i1] = dr * wr - di * wi;
            ldsIm[slice][i1] = dr * wi + di * wr;
        }
        __syncthreads();
    }

    float* outp = A + (size_t)m * (NXS * NXS * 2) + (size_t)row * NXS * 2;
    #pragma unroll
    for (int j = 0; j < 4; ++j) {
        int k  = lane + 64 * j;
        int rk = bitrev8(k);
        *(float2*)(outp + k * 2) = make_float2(ldsRe[slice][rk], ldsIm[slice][rk]);
    }
}

// ---------------------------------------------------------------------------
// Pass 2: FFT along the row axis (stride-256 columns), in place.
// ---------------------------------------------------------------------------
#define CTILE 16
__global__ __launch_bounds__(256) void fft_cols_kernel(float* __restrict__ A) {
    __shared__ float ldsRe[CTILE][257];
    __shared__ float ldsIm[CTILE][257];
    __shared__ float twRe[128], twIm[128];

    const int tid = threadIdx.x;
    const int blk = blockIdx.x;
    const int m   = blk >> 4;             // 16 tiles per image
    const int k0  = (blk & 15) * CTILE;

    if (tid < 128) {
        float a = (float)tid * (1.0f / 128.0f);
        twRe[tid] =  cospif(a);
        twIm[tid] = -sinpif(a);
    }

    float* base = A + (size_t)m * (NXS * NXS * 2);
    #pragma unroll
    for (int it = 0; it < 16; ++it) {
        int li = it * 256 + tid;
        int r  = li >> 4;
        int cc = li & 15;
        float2 v = *(const float2*)(base + ((size_t)r * NXS + k0 + cc) * 2);
        ldsRe[cc][r] = v.x;
        ldsIm[cc][r] = v.y;
    }
    __syncthreads();

    const int slice = tid >> 6;
    const int lane  = tid & 63;

    #pragma unroll
    for (int half = 128; half >= 1; half >>= 1) {
        #pragma unroll
        for (int ci = 0; ci < 4; ++ci) {
            int col = slice * 4 + ci;
            #pragma unroll
            for (int qq = 0; qq < 2; ++qq) {
                int q  = lane + 64 * qq;
                int g  = q / half;
                int j  = q - g * half;
                int i0 = g * 2 * half + j;
                int i1 = i0 + half;
                float ar = ldsRe[col][i0], ai = ldsIm[col][i0];
                float br = ldsRe[col][i1], bi = ldsIm[col][i1];
                ldsRe[col][i0] = ar + br;
                ldsIm[col][i0] = ai + bi;
                float dr = ar - br, di = ai - bi;
                int k = j * (128 / half);
                float wr = twRe[k], wi = twIm[k];
                ldsRe[col][i1] = dr * wr - di * wi;
                ldsIm[col][i1] = dr * wi + di * wr;
            }
        }
        __syncthreads();
    }

    #pragma unroll
    for (int it = 0; it < 16; ++it) {
        int li = it * 256 + tid;
        int ky = li >> 4;
        int cc = li & 15;
        int kx = k0 + cc;
        int rk = bitrev8(ky);
        float s = (((ky + kx) & 1) ? -1.0f : 1.0f) * (1.0f / 256.0f);
        *(float2*)(base + ((size_t)ky * NXS + kx) * 2) =
            make_float2(s * ldsRe[cc][rk], s * ldsIm[cc][rk]);
    }
}

// ---------------------------------------------------------------------------
// Stage 3: out[c,f,n] = mask[f,n] * sum_b Y[c,b,n] * VT[b,f]
// R9 post-mortem: f-tiling regressed (VT-sL1 theory falsified; Y re-reads
// cost 40 us). R10 theory: NT stores ack at HBM (~900 cyc) and vmcnt retires
// IN ORDER, so each iteration's mask-load wait chained on the previous
// iteration's store completion -> per-iter convoy. Fix: normal stores (ack at
// L2, fast vmcnt drain, HW writes back dense) + mask pipeline 2 iters deep.
// Structure otherwise = R8 (best): 1 n/thread, FT=4, yr[30] pinned, no LDS.
// ---------------------------------------------------------------------------
#define FT 4
__global__ __launch_bounds__(256) void project_mask_kernel(
        const float* __restrict__ Y, const float* __restrict__ VT,
        const void* __restrict__ maskT, float* __restrict__ out) {
    const int n = blockIdx.x * 256 + threadIdx.x;
    const int c = blockIdx.y;

    // Detect mask storage: bool-as-byte vs int32 (uniform, scalar loads).
    const unsigned* mw = (const unsigned*)maskT;
    bool byteMode = false;
    #pragma unroll
    for (int i = 0; i < 32; ++i) byteMode |= (mw[i] > 1u);

    // Y column resident in 30 VGPRs (each Y element read from HBM once).
    float yr[NBASIS];
    const float* Yp = Y + (size_t)c * NBASIS * NX + n;
    #pragma unroll
    for (int b = 0; b < NBASIS; ++b) {
        yr[b] = Yp[(size_t)b * NX];
        asm volatile("" : "+v"(yr[b]));   // forbid remat/sink
    }

    const unsigned char* m8  = (const unsigned char*)maskT + n;
    const int*           m32 = (const int*)maskT + n;
    float* outp = out + (size_t)c * NF * NX + n;

    // Mask pipeline, 2 iterations deep.
    unsigned mcur[FT], mnext[FT];
    #pragma unroll
    for (int j = 0; j < FT; ++j) {
        mcur[j]  = byteMode ? (unsigned)m8[(size_t)j * NX]
                            : (unsigned)m32[(size_t)j * NX];
        mnext[j] = byteMode ? (unsigned)m8[(size_t)(FT + j) * NX]
                            : (unsigned)m32[(size_t)(FT + j) * NX];
    }

    #pragma unroll 1
    for (int f0 = 0; f0 < NF; f0 += FT) {
        // Issue loads for iteration f0 + 2*FT (consumed two iterations later).
        unsigned mfar[FT];
        if (f0 + 2 * FT < NF) {
            #pragma unroll
            for (int j = 0; j < FT; ++j)
                mfar[j] = byteMode ? (unsigned)m8[(size_t)(f0 + 2 * FT + j) * NX]
                                   : (unsigned)m32[(size_t)(f0 + 2 * FT + j) * NX];
        }

        float acc[FT];
        #pragma unroll
        for (int j = 0; j < FT; ++j) acc[j] = 0.0f;

        #pragma unroll
        for (int b = 0; b < NBASIS; ++b) {
            float y = yr[b];
            #pragma unroll
            for (int j = 0; j < FT; ++j)
                acc[j] = fmaf(y, VT[b * NF + f0 + j], acc[j]);  // uniform -> SGPR
        }

        #pragma unroll
        for (int j = 0; j < FT; ++j) {
            float o = (mcur[j] != 0u) ? acc[j] : 0.0f;
            outp[(size_t)(f0 + j) * NX] = o;     // normal store: acks at L2
        }

        #pragma unroll
        for (int j = 0; j < FT; ++j) { mcur[j] = mnext[j]; mnext[j] = mfar[j]; }
    }
}

extern "C" void kernel_launch(void* const* d_in, const int* in_sizes, int n_in,
                              void* d_out, int out_size, void* d_ws, size_t ws_size,
                              hipStream_t stream) {
    const float* x    = (const float*)d_in[0];   // (30,256,256,2) f32
    const float* csm  = (const float*)d_in[1];   // (8,256,256,2) f32
    const float* VT   = (const float*)d_in[2];   // (30,200) f32
    const void*  mask = d_in[3];                 // (200,131072) bool/int
    float* out = (float*)d_out;                  // (8,200,131072) f32
    float* A   = (float*)d_ws;                   // 240*256*256*2 f32 = 125.8 MB

    fft_rows_kernel<<<NIMG * 64, 256, 0, stream>>>(x, csm, A);
    fft_cols_kernel<<<NIMG * 16, 256, 0, stream>>>(A);
    project_mask_kernel<<<dim3(NX / 256, NCH), 256, 0, stream>>>(A, VT, mask, out);
}

// Round 11
// 477.114 us; speedup vs baseline: 1.2292x; 1.2292x over previous
//
#include <hip/hip_runtime.h>

#define NCH    8
#define NBASIS 30
#define NXS    256
#define NF     200
#define NX     (NXS*NXS*2)      // 131072
#define NIMG   (NCH*NBASIS)     // 240
#define MT_STRIDE 256           // padded row stride of transposed mask

typedef float    f32x2 __attribute__((ext_vector_type(2)));
typedef unsigned u32x4 __attribute__((ext_vector_type(4)));

__device__ __forceinline__ int bitrev8(int v) {
    return (int)(__builtin_bitreverse32((unsigned)v) >> 24);
}

// ---------------------------------------------------------------------------
// Pass 1: w = (x * csm) * (-1)^(row+col); FFT along the contiguous (col) axis.
// ---------------------------------------------------------------------------
__global__ __launch_bounds__(256) void fft_rows_kernel(
        const float* __restrict__ x, const float* __restrict__ csm,
        float* __restrict__ A) {
    __shared__ float ldsRe[4][256];
    __shared__ float ldsIm[4][256];
    __shared__ float twRe[128], twIm[128];

    const int tid   = threadIdx.x;
    const int slice = tid >> 6;
    const int lane  = tid & 63;
    const int blk   = blockIdx.x;       // m*64 + rowTile
    const int m     = blk >> 6;
    const int row   = ((blk & 63) << 2) + slice;
    const int c     = m / NBASIS;
    const int b     = m - c * NBASIS;

    if (tid < 128) {
        float a = (float)tid * (1.0f / 128.0f);   // theta = pi * a
        twRe[tid] =  cospif(a);
        twIm[tid] = -sinpif(a);
    }

    const float* xr = x   + ((size_t)(b * NXS + row) * NXS) * 2;
    const float* cr = csm + ((size_t)(c * NXS + row) * NXS) * 2;
    #pragma unroll
    for (int j = 0; j < 4; ++j) {
        int col = lane + 64 * j;
        float2 xv = *(const float2*)(xr + col * 2);
        float2 cv = *(const float2*)(cr + col * 2);
        float s = ((row + col) & 1) ? -1.0f : 1.0f;
        ldsRe[slice][col] = s * (xv.x * cv.x - xv.y * cv.y);
        ldsIm[slice][col] = s * (xv.x * cv.y + xv.y * cv.x);
    }
    __syncthreads();

    #pragma unroll
    for (int half = 128; half >= 1; half >>= 1) {
        #pragma unroll
        for (int qq = 0; qq < 2; ++qq) {
            int q  = lane + 64 * qq;
            int g  = q / half;
            int j  = q - g * half;
            int i0 = g * 2 * half + j;
            int i1 = i0 + half;
            float ar = ldsRe[slice][i0], ai = ldsIm[slice][i0];
            float br = ldsRe[slice][i1], bi = ldsIm[slice][i1];
            ldsRe[slice][i0] = ar + br;
            ldsIm[slice][i0] = ai + bi;
            float dr = ar - br, di = ai - bi;
            int k = j * (128 / half);
            float wr = twRe[k], wi = twIm[k];
            ldsRe[slice][i1] = dr * wr - di * wi;
            ldsIm[slice][i1] = dr * wi + di * wr;
        }
        __syncthreads();
    }

    float* outp = A + (size_t)m * (NXS * NXS * 2) + (size_t)row * NXS * 2;
    #pragma unroll
    for (int j = 0; j < 4; ++j) {
        int k  = lane + 64 * j;
        int rk = bitrev8(k);
        *(float2*)(outp + k * 2) = make_float2(ldsRe[slice][rk], ldsIm[slice][rk]);
    }
}

// ---------------------------------------------------------------------------
// Pass 2: FFT along the row axis (stride-256 columns), in place.
// ---------------------------------------------------------------------------
#define CTILE 16
__global__ __launch_bounds__(256) void fft_cols_kernel(float* __restrict__ A) {
    __shared__ float ldsRe[CTILE][257];
    __shared__ float ldsIm[CTILE][257];
    __shared__ float twRe[128], twIm[128];

    const int tid = threadIdx.x;
    const int blk = blockIdx.x;
    const int m   = blk >> 4;             // 16 tiles per image
    const int k0  = (blk & 15) * CTILE;

    if (tid < 128) {
        float a = (float)tid * (1.0f / 128.0f);
        twRe[tid] =  cospif(a);
        twIm[tid] = -sinpif(a);
    }

    float* base = A + (size_t)m * (NXS * NXS * 2);
    #pragma unroll
    for (int it = 0; it < 16; ++it) {
        int li = it * 256 + tid;
        int r  = li >> 4;
        int cc = li & 15;
        float2 v = *(const float2*)(base + ((size_t)r * NXS + k0 + cc) * 2);
        ldsRe[cc][r] = v.x;
        ldsIm[cc][r] = v.y;
    }
    __syncthreads();

    const int slice = tid >> 6;
    const int lane  = tid & 63;

    #pragma unroll
    for (int half = 128; half >= 1; half >>= 1) {
        #pragma unroll
        for (int ci = 0; ci < 4; ++ci) {
            int col = slice * 4 + ci;
            #pragma unroll
            for (int qq = 0; qq < 2; ++qq) {
                int q  = lane + 64 * qq;
                int g  = q / half;
                int j  = q - g * half;
                int i0 = g * 2 * half + j;
                int i1 = i0 + half;
                float ar = ldsRe[col][i0], ai = ldsIm[col][i0];
                float br = ldsRe[col][i1], bi = ldsIm[col][i1];
                ldsRe[col][i0] = ar + br;
                ldsIm[col][i0] = ai + bi;
                float dr = ar - br, di = ai - bi;
                int k = j * (128 / half);
                float wr = twRe[k], wi = twIm[k];
                ldsRe[col][i1] = dr * wr - di * wi;
                ldsIm[col][i1] = dr * wi + di * wr;
            }
        }
        __syncthreads();
    }

    #pragma unroll
    for (int it = 0; it < 16; ++it) {
        int li = it * 256 + tid;
        int ky = li >> 4;
        int cc = li & 15;
        int kx = k0 + cc;
        int rk = bitrev8(ky);
        float s = (((ky + kx) & 1) ? -1.0f : 1.0f) * (1.0f / 256.0f);
        *(float2*)(base + ((size_t)ky * NXS + kx) * 2) =
            make_float2(s * ldsRe[cc][rk], s * ldsIm[cc][rk]);
    }
}

// ---------------------------------------------------------------------------
// Mask transpose: mt[n][f] (byte, 256-B row stride) from maskT[f][n]
// (byte or int32, sniffed). 32f x 64n tiles through LDS; ~60 MB traffic.
// ---------------------------------------------------------------------------
__global__ __launch_bounds__(256) void transpose_mask_kernel(
        const void* __restrict__ maskT, unsigned char* __restrict__ mt) {
    __shared__ unsigned char lds[32][68];   // pad 68 = 4*17 -> no bank clash

    const int tid  = threadIdx.x;
    const int n0   = blockIdx.x * 64;
    const int fb   = blockIdx.y * 32;
    const int fcnt = (NF - fb) < 32 ? (NF - fb) : 32;   // 32 or 8

    const unsigned* mw = (const unsigned*)maskT;
    bool byteMode = false;
    #pragma unroll
    for (int i = 0; i < 32; ++i) byteMode |= (mw[i] > 1u);

    if (byteMode) {
        const unsigned char* m8 = (const unsigned char*)maskT;
        for (int i = tid; i < 32 * 16; i += 256) {      // 16 dwords/row
            int row = i >> 4, dw = i & 15;
            if (row < fcnt) {
                unsigned w = *(const unsigned*)(m8 + (size_t)(fb + row) * NX
                                                + n0 + dw * 4);
                *(unsigned*)&lds[row][dw * 4] = w;
            }
        }
    } else {
        const int* m32 = (const int*)maskT;
        for (int i = tid; i < 32 * 64; i += 256) {
            int row = i >> 6, col = i & 63;
            if (row < fcnt)
                lds[row][col] =
                    (unsigned char)(m32[(size_t)(fb + row) * NX + n0 + col] != 0);
        }
    }
    __syncthreads();

    if (fcnt == 32) {
        for (int i = tid; i < 64 * 8; i += 256) {       // 8 dwords per n-row
            int nn = i >> 3, d = i & 7;
            unsigned w = (unsigned)lds[4 * d + 0][nn]
                       | ((unsigned)lds[4 * d + 1][nn] << 8)
                       | ((unsigned)lds[4 * d + 2][nn] << 16)
                       | ((unsigned)lds[4 * d + 3][nn] << 24);
            *(unsigned*)(mt + (size_t)(n0 + nn) * MT_STRIDE + fb + 4 * d) = w;
        }
    } else {                                            // tail tile: 8 f
        for (int i = tid; i < 64 * 2; i += 256) {
            int nn = i >> 1, d = i & 1;
            unsigned w = (unsigned)lds[4 * d + 0][nn]
                       | ((unsigned)lds[4 * d + 1][nn] << 8)
                       | ((unsigned)lds[4 * d + 2][nn] << 16)
                       | ((unsigned)lds[4 * d + 3][nn] << 24);
            *(unsigned*)(mt + (size_t)(n0 + nn) * MT_STRIDE + fb + 4 * d) = w;
        }
    }
}

// ---------------------------------------------------------------------------
// Stage 3: out[c,f,n] = mask[f,n] * sum_b Y[c,b,n] * VT[b,f]
// R10 post-mortem: normal stores regressed (+127 us) -> NT stores restored.
// R8 structure kept (1 n/thread, FT=4, yr[30] pinned, no LDS). New: mask read
// from the transposed mt[n][f] as 13 dwordx4 loads per thread (1 KB/wave-instr
// vs 64 B), software-pipelined one 16-f group (~1000 cyc) ahead with 8
// in-flight VGPRs -> mask L3 latency (mask > 4MB per-XCD L2) hidden.
// Live set ~56 VGPR <= 64 -> 8 waves/SIMD, no spill.
// ---------------------------------------------------------------------------
#define FT 4
__global__ __launch_bounds__(256) void project_mask_kernel(
        const float* __restrict__ Y, const float* __restrict__ VT,
        const unsigned char* __restrict__ mt, float* __restrict__ out) {
    const int n = blockIdx.x * 256 + threadIdx.x;
    const int c = blockIdx.y;

    // Y column resident in 30 VGPRs (each Y element read from HBM once).
    float yr[NBASIS];
    const float* Yp = Y + (size_t)c * NBASIS * NX + n;
    #pragma unroll
    for (int b = 0; b < NBASIS; ++b) {
        yr[b] = Yp[(size_t)b * NX];
        asm volatile("" : "+v"(yr[b]));   // forbid remat/sink
    }

    const u32x4* mrow = (const u32x4*)(mt + (size_t)n * MT_STRIDE);
    float* outp = out + (size_t)c * NF * NX + n;

    u32x4 mcur = mrow[0];

    #pragma unroll 1
    for (int g = 0; g < 13; ++g) {        // 16 f per group
        u32x4 mnext = (u32x4)(0u, 0u, 0u, 0u);
        if (g < 12) mnext = mrow[g + 1];

        #pragma unroll
        for (int s = 0; s < 4; ++s) {
            const int f0 = g * 16 + s * 4;
            if (f0 >= NF) break;          // uniform guard (tail group)
            unsigned w = mcur[s];

            float acc[FT];
            #pragma unroll
            for (int j = 0; j < FT; ++j) acc[j] = 0.0f;

            #pragma unroll
            for (int b = 0; b < NBASIS; ++b) {
                float y = yr[b];
                #pragma unroll
                for (int j = 0; j < FT; ++j)
                    acc[j] = fmaf(y, VT[b * NF + f0 + j], acc[j]);  // SGPR vt
            }

            #pragma unroll
            for (int j = 0; j < FT; ++j) {
                float o = ((w >> (8 * j)) & 0xFFu) ? acc[j] : 0.0f;
                __builtin_nontemporal_store(o, outp + (size_t)(f0 + j) * NX);
            }
        }
        mcur = mnext;
    }
}

extern "C" void kernel_launch(void* const* d_in, const int* in_sizes, int n_in,
                              void* d_out, int out_size, void* d_ws, size_t ws_size,
                              hipStream_t stream) {
    const float* x    = (const float*)d_in[0];   // (30,256,256,2) f32
    const float* csm  = (const float*)d_in[1];   // (8,256,256,2) f32
    const float* VT   = (const float*)d_in[2];   // (30,200) f32
    const void*  mask = d_in[3];                 // (200,131072) bool/int
    float* out = (float*)d_out;                  // (8,200,131072) f32

    float*         A  = (float*)d_ws;                                  // 125.8 MB
    unsigned char* mt = (unsigned char*)d_ws + (size_t)128 * 1024 * 1024; // 33.6 MB

    transpose_mask_kernel<<<dim3(NX / 64, 7), 256, 0, stream>>>(mask, mt);
    fft_rows_kernel<<<NIMG * 64, 256, 0, stream>>>(x, csm, A);
    fft_cols_kernel<<<NIMG * 16, 256, 0, stream>>>(A);
    project_mask_kernel<<<dim3(NX / 256, NCH), 256, 0, stream>>>(A, VT, mt, out);
}

// Round 12
// 441.128 us; speedup vs baseline: 1.3294x; 1.0816x over previous
//
#include <hip/hip_runtime.h>

#define NCH    8
#define NBASIS 30
#define NXS    256
#define NF     200
#define NX     (NXS*NXS*2)      // 131072
#define NIMG   (NCH*NBASIS)     // 240
#define MT_STRIDE 256           // padded row stride of transposed mask
#define NFT    13               // f-tiles of 16 (13*16 = 208 >= 200)

typedef float    f32x2  __attribute__((ext_vector_type(2)));
typedef float    f32x4  __attribute__((ext_vector_type(4)));
typedef unsigned u32x4  __attribute__((ext_vector_type(4)));
typedef unsigned u32x2  __attribute__((ext_vector_type(2)));
typedef short    bf16x8 __attribute__((ext_vector_type(8)));

__device__ __forceinline__ int bitrev8(int v) {
    return (int)(__builtin_bitreverse32((unsigned)v) >> 24);
}

__device__ __forceinline__ unsigned short f2bf(float f) {   // RNE f32->bf16
    unsigned u = __float_as_uint(f);
    return (unsigned short)((u + 0x7FFFu + ((u >> 16) & 1u)) >> 16);
}

// ---------------------------------------------------------------------------
// Pass 1: w = (x * csm) * (-1)^(row+col); FFT along the contiguous (col) axis.
// ---------------------------------------------------------------------------
__global__ __launch_bounds__(256) void fft_rows_kernel(
        const float* __restrict__ x, const float* __restrict__ csm,
        float* __restrict__ A) {
    __shared__ float ldsRe[4][256];
    __shared__ float ldsIm[4][256];
    __shared__ float twRe[128], twIm[128];

    const int tid   = threadIdx.x;
    const int slice = tid >> 6;
    const int lane  = tid & 63;
    const int blk   = blockIdx.x;       // m*64 + rowTile
    const int m     = blk >> 6;
    const int row   = ((blk & 63) << 2) + slice;
    const int c     = m / NBASIS;
    const int b     = m - c * NBASIS;

    if (tid < 128) {
        float a = (float)tid * (1.0f / 128.0f);   // theta = pi * a
        twRe[tid] =  cospif(a);
        twIm[tid] = -sinpif(a);
    }

    const float* xr = x   + ((size_t)(b * NXS + row) * NXS) * 2;
    const float* cr = csm + ((size_t)(c * NXS + row) * NXS) * 2;
    #pragma unroll
    for (int j = 0; j < 4; ++j) {
        int col = lane + 64 * j;
        float2 xv = *(const float2*)(xr + col * 2);
        float2 cv = *(const float2*)(cr + col * 2);
        float s = ((row + col) & 1) ? -1.0f : 1.0f;
        ldsRe[slice][col] = s * (xv.x * cv.x - xv.y * cv.y);
        ldsIm[slice][col] = s * (xv.x * cv.y + xv.y * cv.x);
    }
    __syncthreads();

    #pragma unroll
    for (int half = 128; half >= 1; half >>= 1) {
        #pragma unroll
        for (int qq = 0; qq < 2; ++qq) {
            int q  = lane + 64 * qq;
            int g  = q / half;
            int j  = q - g * half;
            int i0 = g * 2 * half + j;
            int i1 = i0 + half;
            float ar = ldsRe[slice][i0], ai = ldsIm[slice][i0];
            float br = ldsRe[slice][i1], bi = ldsIm[slice][i1];
            ldsRe[slice][i0] = ar + br;
            ldsIm[slice][i0] = ai + bi;
            float dr = ar - br, di = ai - bi;
            int k = j * (128 / half);
            float wr = twRe[k], wi = twIm[k];
            ldsRe[slice][i1] = dr * wr - di * wi;
            ldsIm[slice][i1] = dr * wi + di * wr;
        }
        __syncthreads();
    }

    float* outp = A + (size_t)m * (NXS * NXS * 2) + (size_t)row * NXS * 2;
    #pragma unroll
    for (int j = 0; j < 4; ++j) {
        int k  = lane + 64 * j;
        int rk = bitrev8(k);
        *(float2*)(outp + k * 2) = make_float2(ldsRe[slice][rk], ldsIm[slice][rk]);
    }
}

// ---------------------------------------------------------------------------
// Pass 2: FFT along the row axis; OUTPUT IS bf16 (Abf), consumed by the MFMA
// stage. The fp32 writeback is dropped (saves 126 MB of HBM writes).
// ---------------------------------------------------------------------------
#define CTILE 16
__global__ __launch_bounds__(256) void fft_cols_kernel(
        const float* __restrict__ A, unsigned short* __restrict__ Abf) {
    __shared__ float ldsRe[CTILE][257];
    __shared__ float ldsIm[CTILE][257];
    __shared__ float twRe[128], twIm[128];

    const int tid = threadIdx.x;
    const int blk = blockIdx.x;
    const int m   = blk >> 4;             // 16 tiles per image
    const int k0  = (blk & 15) * CTILE;

    if (tid < 128) {
        float a = (float)tid * (1.0f / 128.0f);
        twRe[tid] =  cospif(a);
        twIm[tid] = -sinpif(a);
    }

    const float* base = A + (size_t)m * (NXS * NXS * 2);
    #pragma unroll
    for (int it = 0; it < 16; ++it) {
        int li = it * 256 + tid;
        int r  = li >> 4;
        int cc = li & 15;
        float2 v = *(const float2*)(base + ((size_t)r * NXS + k0 + cc) * 2);
        ldsRe[cc][r] = v.x;
        ldsIm[cc][r] = v.y;
    }
    __syncthreads();

    const int slice = tid >> 6;
    const int lane  = tid & 63;

    #pragma unroll
    for (int half = 128; half >= 1; half >>= 1) {
        #pragma unroll
        for (int ci = 0; ci < 4; ++ci) {
            int col = slice * 4 + ci;
            #pragma unroll
            for (int qq = 0; qq < 2; ++qq) {
                int q  = lane + 64 * qq;
                int g  = q / half;
                int j  = q - g * half;
                int i0 = g * 2 * half + j;
                int i1 = i0 + half;
                float ar = ldsRe[col][i0], ai = ldsIm[col][i0];
                float br = ldsRe[col][i1], bi = ldsIm[col][i1];
                ldsRe[col][i0] = ar + br;
                ldsIm[col][i0] = ai + bi;
                float dr = ar - br, di = ai - bi;
                int k = j * (128 / half);
                float wr = twRe[k], wi = twIm[k];
                ldsRe[col][i1] = dr * wr - di * wi;
                ldsIm[col][i1] = dr * wi + di * wr;
            }
        }
        __syncthreads();
    }

    unsigned short* obase = Abf + (size_t)m * NX;
    #pragma unroll
    for (int it = 0; it < 16; ++it) {
        int li = it * 256 + tid;
        int ky = li >> 4;
        int cc = li & 15;
        int kx = k0 + cc;
        int rk = bitrev8(ky);
        float s = (((ky + kx) & 1) ? -1.0f : 1.0f) * (1.0f / 256.0f);
        unsigned pack = ((unsigned)f2bf(s * ldsIm[cc][rk]) << 16)
                      |  (unsigned)f2bf(s * ldsRe[cc][rk]);
        *(unsigned*)(obase + ((size_t)ky * NXS + kx) * 2) = pack;
    }
}

// ---------------------------------------------------------------------------
// Mask transpose: mt[n][f] (byte, 256-B row stride) from maskT[f][n]
// (byte or int32, sniffed). 32f x 64n tiles through LDS.
// ---------------------------------------------------------------------------
__global__ __launch_bounds__(256) void transpose_mask_kernel(
        const void* __restrict__ maskT, unsigned char* __restrict__ mt) {
    __shared__ unsigned char lds[32][68];

    const int tid  = threadIdx.x;
    const int n0   = blockIdx.x * 64;
    const int fb   = blockIdx.y * 32;
    const int fcnt = (NF - fb) < 32 ? (NF - fb) : 32;   // 32 or 8

    const unsigned* mw = (const unsigned*)maskT;
    bool byteMode = false;
    #pragma unroll
    for (int i = 0; i < 32; ++i) byteMode |= (mw[i] > 1u);

    if (byteMode) {
        const unsigned char* m8 = (const unsigned char*)maskT;
        for (int i = tid; i < 32 * 16; i += 256) {      // 16 dwords/row
            int row = i >> 4, dw = i & 15;
            if (row < fcnt) {
                unsigned w = *(const unsigned*)(m8 + (size_t)(fb + row) * NX
                                                + n0 + dw * 4);
                *(unsigned*)&lds[row][dw * 4] = w;
            }
        }
    } else {
        const int* m32 = (const int*)maskT;
        for (int i = tid; i < 32 * 64; i += 256) {
            int row = i >> 6, col = i & 63;
            if (row < fcnt)
                lds[row][col] =
                    (unsigned char)(m32[(size_t)(fb + row) * NX + n0 + col] != 0);
        }
    }
    __syncthreads();

    if (fcnt == 32) {
        for (int i = tid; i < 64 * 8; i += 256) {       // 8 dwords per n-row
            int nn = i >> 3, d = i & 7;
            unsigned w = (unsigned)lds[4 * d + 0][nn]
                       | ((unsigned)lds[4 * d + 1][nn] << 8)
                       | ((unsigned)lds[4 * d + 2][nn] << 16)
                       | ((unsigned)lds[4 * d + 3][nn] << 24);
            *(unsigned*)(mt + (size_t)(n0 + nn) * MT_STRIDE + fb + 4 * d) = w;
        }
    } else {
        for (int i = tid; i < 64 * 2; i += 256) {
            int nn = i >> 1, d = i & 1;
            unsigned w = (unsigned)lds[4 * d + 0][nn]
                       | ((unsigned)lds[4 * d + 1][nn] << 8)
                       | ((unsigned)lds[4 * d + 2][nn] << 16)
                       | ((unsigned)lds[4 * d + 3][nn] << 24);
            *(unsigned*)(mt + (size_t)(n0 + nn) * MT_STRIDE + fb + 4 * d) = w;
        }
    }
}

// ---------------------------------------------------------------------------
// VT -> fragment-ordered bf16: VTfrag[ft][lane][j] = VT[k][f], k=(lane>>4)*8+j
// (0 for k>=30), f = ft*16 + (lane&15) (0 for f>=200). One dwordx4 per wave
// per f-tile in the GEMM = coalesced A-frag load.
// ---------------------------------------------------------------------------
__global__ __launch_bounds__(256) void vt_prep_kernel(
        const float* __restrict__ VT, unsigned short* __restrict__ VTfrag) {
    int i = blockIdx.x * 256 + threadIdx.x;
    if (i >= NFT * 512) return;
    int ft = i >> 9, r = i & 511, lane = r >> 3, j = r & 7;
    int k = (lane >> 4) * 8 + j;
    int f = ft * 16 + (lane & 15);
    unsigned short v = 0;
    if (k < NBASIS && f < NF) v = f2bf(VT[k * NF + f]);
    VTfrag[i] = v;
}

// ---------------------------------------------------------------------------
// Stage 3 via MFMA: out[c,f,n] = mask[f,n] * sum_b VT[b,f] * Y[b,n].
// R11 post-mortem: 4 latency theories failed; the fp32 VALU structure itself
// (2 FLOP/instr, per-iter convoys) is the cost. GEMM K=30->pad 32, one
// mfma_f32_16x16x32_bf16 per 16f x 16n tile (512 MAC/instr). Block = 4 waves,
// 256 n x all f x 1 c. Y tile (32 x 256 bf16) staged once in LDS; B-frags
// (16 VGPR) live across the whole block; A-frags stream from VTfrag
// (coalesced dwordx4, L2-hot). A/B internal k-order is self-consistent (same
// bijection both sides); C/D layout = m89-verified col=lane&15,
// row=(lane>>4)*4+reg. Epilogue: mt dword (4 f per lane), cndmask, NT store.
// ---------------------------------------------------------------------------
__global__ __launch_bounds__(256) void project_mfma_kernel(
        const unsigned short* __restrict__ Abf,    // [240][NX] bf16
        const unsigned short* __restrict__ VTfrag, // [13][64][8] bf16
        const unsigned char*  __restrict__ mt,     // [NX][256] bytes
        float* __restrict__ out) {
    __shared__ unsigned short ylds[32][264];       // 528-B rows, 16-B aligned

    const int tid = threadIdx.x;
    const int c   = blockIdx.y;
    const int n0  = blockIdx.x * 256;

    // Stage Y tile: rows b=0..29 from Abf, rows 30/31 zero (K padding).
    for (int i = tid; i < 32 * 32; i += 256) {
        int row = i >> 5, seg = i & 31;
        u32x4 v = (u32x4)(0u, 0u, 0u, 0u);
        if (row < NBASIS)
            v = *(const u32x4*)(Abf + ((size_t)(c * NBASIS + row)) * NX
                                + n0 + seg * 8);
        *(u32x4*)&ylds[row][seg * 8] = v;
    }
    __syncthreads();

    const int lane = tid & 63;
    const int wv   = tid >> 6;          // wave's 64-n sub-strip
    const int ksec = lane >> 4;
    const int fr   = lane & 15;
    const int n0w  = n0 + wv * 64;

    // B-frags: 4 x 8 bf16 (frag fn covers n = n0w + fn*16 + fr).
    bf16x8 bfrag[4];
    #pragma unroll
    for (int fn = 0; fn < 4; ++fn) {
        #pragma unroll
        for (int j = 0; j < 8; ++j)
            bfrag[fn][j] = (short)ylds[ksec * 8 + j][wv * 64 + fn * 16 + fr];
    }

    const unsigned short* vtf = VTfrag + lane * 8;
    float* outc = out + (size_t)c * NF * NX;

    #pragma unroll 1
    for (int ft = 0; ft < NFT; ++ft) {
        bf16x8 afrag = *(const bf16x8*)(vtf + ft * 512);

        unsigned md[4];
        #pragma unroll
        for (int fn = 0; fn < 4; ++fn) {
            int nn = n0w + fn * 16 + fr;
            md[fn] = *(const unsigned*)(mt + (size_t)nn * MT_STRIDE
                                        + ft * 16 + ksec * 4);
        }

        #pragma unroll
        for (int fn = 0; fn < 4; ++fn) {
            f32x4 d = __builtin_amdgcn_mfma_f32_16x16x32_bf16(
                afrag, bfrag[fn], (f32x4)(0.f, 0.f, 0.f, 0.f), 0, 0, 0);
            int nn = n0w + fn * 16 + fr;
            #pragma unroll
            for (int r = 0; r < 4; ++r) {
                int f = ft * 16 + ksec * 4 + r;
                if (f < NF) {
                    float o = ((md[fn] >> (8 * r)) & 0xFFu) ? d[r] : 0.0f;
                    __builtin_nontemporal_store(o, outc + (size_t)f * NX + nn);
                }
            }
        }
    }
}

extern "C" void kernel_launch(void* const* d_in, const int* in_sizes, int n_in,
                              void* d_out, int out_size, void* d_ws, size_t ws_size,
                              hipStream_t stream) {
    const float* x    = (const float*)d_in[0];   // (30,256,256,2) f32
    const float* csm  = (const float*)d_in[1];   // (8,256,256,2) f32
    const float* VT   = (const float*)d_in[2];   // (30,200) f32
    const void*  mask = d_in[3];                 // (200,131072) bool/int
    float* out = (float*)d_out;                  // (8,200,131072) f32

    char* ws = (char*)d_ws;
    float*          A      = (float*)ws;                              // 125.8 MB
    unsigned short* Abf    = (unsigned short*)(ws + ((size_t)128 << 20)); // 62.9 MB
    unsigned char*  mt     = (unsigned char*)(ws + ((size_t)192 << 20));  // 33.6 MB
    unsigned short* VTfrag = (unsigned short*)(ws + ((size_t)232 << 20)); // 13.3 KB

    vt_prep_kernel<<<(NFT * 512 + 255) / 256, 256, 0, stream>>>(VT, VTfrag);
    transpose_mask_kernel<<<dim3(NX / 64, 7), 256, 0, stream>>>(mask, mt);
    fft_rows_kernel<<<NIMG * 64, 256, 0, stream>>>(x, csm, A);
    fft_cols_kernel<<<NIMG * 16, 256, 0, stream>>>(A, Abf);
    project_mfma_kernel<<<dim3(NX / 256, NCH), 256, 0, stream>>>(Abf, VTfrag, mt, out);
}

// Round 13
// 424.219 us; speedup vs baseline: 1.3824x; 1.0399x over previous
//
#include <hip/hip_runtime.h>

#define NCH    8
#define NBASIS 30
#define NXS    256
#define NF     200
#define NX     (NXS*NXS*2)      // 131072
#define NIMG   (NCH*NBASIS)     // 240
#define MT_STRIDE 256           // padded row stride of transposed mask
#define NFT    13               // f-tiles of 16 (13*16 = 208 >= 200)

typedef float    f32x2  __attribute__((ext_vector_type(2)));
typedef float    f32x4  __attribute__((ext_vector_type(4)));
typedef unsigned u32x4  __attribute__((ext_vector_type(4)));
typedef short    bf16x8 __attribute__((ext_vector_type(8)));

__device__ __forceinline__ int bitrev8(int v) {
    return (int)(__builtin_bitreverse32((unsigned)v) >> 24);
}

__device__ __forceinline__ unsigned short f2bf(float f) {   // RNE f32->bf16
    unsigned u = __float_as_uint(f);
    return (unsigned short)((u + 0x7FFFu + ((u >> 16) & 1u)) >> 16);
}

// ---------------------------------------------------------------------------
// Pass 1: w = (x * csm) * (-1)^(row+col); FFT along the contiguous (col) axis.
// ---------------------------------------------------------------------------
__global__ __launch_bounds__(256) void fft_rows_kernel(
        const float* __restrict__ x, const float* __restrict__ csm,
        float* __restrict__ A) {
    __shared__ float ldsRe[4][256];
    __shared__ float ldsIm[4][256];
    __shared__ float twRe[128], twIm[128];

    const int tid   = threadIdx.x;
    const int slice = tid >> 6;
    const int lane  = tid & 63;
    const int blk   = blockIdx.x;       // m*64 + rowTile
    const int m     = blk >> 6;
    const int row   = ((blk & 63) << 2) + slice;
    const int c     = m / NBASIS;
    const int b     = m - c * NBASIS;

    if (tid < 128) {
        float a = (float)tid * (1.0f / 128.0f);   // theta = pi * a
        twRe[tid] =  cospif(a);
        twIm[tid] = -sinpif(a);
    }

    const float* xr = x   + ((size_t)(b * NXS + row) * NXS) * 2;
    const float* cr = csm + ((size_t)(c * NXS + row) * NXS) * 2;
    #pragma unroll
    for (int j = 0; j < 4; ++j) {
        int col = lane + 64 * j;
        float2 xv = *(const float2*)(xr + col * 2);
        float2 cv = *(const float2*)(cr + col * 2);
        float s = ((row + col) & 1) ? -1.0f : 1.0f;
        ldsRe[slice][col] = s * (xv.x * cv.x - xv.y * cv.y);
        ldsIm[slice][col] = s * (xv.x * cv.y + xv.y * cv.x);
    }
    __syncthreads();

    #pragma unroll
    for (int half = 128; half >= 1; half >>= 1) {
        #pragma unroll
        for (int qq = 0; qq < 2; ++qq) {
            int q  = lane + 64 * qq;
            int g  = q / half;
            int j  = q - g * half;
            int i0 = g * 2 * half + j;
            int i1 = i0 + half;
            float ar = ldsRe[slice][i0], ai = ldsIm[slice][i0];
            float br = ldsRe[slice][i1], bi = ldsIm[slice][i1];
            ldsRe[slice][i0] = ar + br;
            ldsIm[slice][i0] = ai + bi;
            float dr = ar - br, di = ai - bi;
            int k = j * (128 / half);
            float wr = twRe[k], wi = twIm[k];
            ldsRe[slice][i1] = dr * wr - di * wi;
            ldsIm[slice][i1] = dr * wi + di * wr;
        }
        __syncthreads();
    }

    float* outp = A + (size_t)m * (NXS * NXS * 2) + (size_t)row * NXS * 2;
    #pragma unroll
    for (int j = 0; j < 4; ++j) {
        int k  = lane + 64 * j;
        int rk = bitrev8(k);
        *(float2*)(outp + k * 2) = make_float2(ldsRe[slice][rk], ldsIm[slice][rk]);
    }
}

// ---------------------------------------------------------------------------
// Pass 2: FFT along the row axis; OUTPUT IS bf16 (Abf) for the MFMA stage.
// ---------------------------------------------------------------------------
#define CTILE 16
__global__ __launch_bounds__(256) void fft_cols_kernel(
        const float* __restrict__ A, unsigned short* __restrict__ Abf) {
    __shared__ float ldsRe[CTILE][257];
    __shared__ float ldsIm[CTILE][257];
    __shared__ float twRe[128], twIm[128];

    const int tid = threadIdx.x;
    const int blk = blockIdx.x;
    const int m   = blk >> 4;             // 16 tiles per image
    const int k0  = (blk & 15) * CTILE;

    if (tid < 128) {
        float a = (float)tid * (1.0f / 128.0f);
        twRe[tid] =  cospif(a);
        twIm[tid] = -sinpif(a);
    }

    const float* base = A + (size_t)m * (NXS * NXS * 2);
    #pragma unroll
    for (int it = 0; it < 16; ++it) {
        int li = it * 256 + tid;
        int r  = li >> 4;
        int cc = li & 15;
        float2 v = *(const float2*)(base + ((size_t)r * NXS + k0 + cc) * 2);
        ldsRe[cc][r] = v.x;
        ldsIm[cc][r] = v.y;
    }
    __syncthreads();

    const int slice = tid >> 6;
    const int lane  = tid & 63;

    #pragma unroll
    for (int half = 128; half >= 1; half >>= 1) {
        #pragma unroll
        for (int ci = 0; ci < 4; ++ci) {
            int col = slice * 4 + ci;
            #pragma unroll
            for (int qq = 0; qq < 2; ++qq) {
                int q  = lane + 64 * qq;
                int g  = q / half;
                int j  = q - g * half;
                int i0 = g * 2 * half + j;
                int i1 = i0 + half;
                float ar = ldsRe[col][i0], ai = ldsIm[col][i0];
                float br = ldsRe[col][i1], bi = ldsIm[col][i1];
                ldsRe[col][i0] = ar + br;
                ldsIm[col][i0] = ai + bi;
                float dr = ar - br, di = ai - bi;
                int k = j * (128 / half);
                float wr = twRe[k], wi = twIm[k];
                ldsRe[col][i1] = dr * wr - di * wi;
                ldsIm[col][i1] = dr * wi + di * wr;
            }
        }
        __syncthreads();
    }

    unsigned short* obase = Abf + (size_t)m * NX;
    #pragma unroll
    for (int it = 0; it < 16; ++it) {
        int li = it * 256 + tid;
        int ky = li >> 4;
        int cc = li & 15;
        int kx = k0 + cc;
        int rk = bitrev8(ky);
        float s = (((ky + kx) & 1) ? -1.0f : 1.0f) * (1.0f / 256.0f);
        unsigned pack = ((unsigned)f2bf(s * ldsIm[cc][rk]) << 16)
                      |  (unsigned)f2bf(s * ldsRe[cc][rk]);
        *(unsigned*)(obase + ((size_t)ky * NXS + kx) * 2) = pack;
    }
}

// ---------------------------------------------------------------------------
// Mask transpose: mt[n][f] (byte, 256-B row stride) from maskT[f][n].
// ---------------------------------------------------------------------------
__global__ __launch_bounds__(256) void transpose_mask_kernel(
        const void* __restrict__ maskT, unsigned char* __restrict__ mt) {
    __shared__ unsigned char lds[32][68];

    const int tid  = threadIdx.x;
    const int n0   = blockIdx.x * 64;
    const int fb   = blockIdx.y * 32;
    const int fcnt = (NF - fb) < 32 ? (NF - fb) : 32;   // 32 or 8

    const unsigned* mw = (const unsigned*)maskT;
    bool byteMode = false;
    #pragma unroll
    for (int i = 0; i < 32; ++i) byteMode |= (mw[i] > 1u);

    if (byteMode) {
        const unsigned char* m8 = (const unsigned char*)maskT;
        for (int i = tid; i < 32 * 16; i += 256) {      // 16 dwords/row
            int row = i >> 4, dw = i & 15;
            if (row < fcnt) {
                unsigned w = *(const unsigned*)(m8 + (size_t)(fb + row) * NX
                                                + n0 + dw * 4);
                *(unsigned*)&lds[row][dw * 4] = w;
            }
        }
    } else {
        const int* m32 = (const int*)maskT;
        for (int i = tid; i < 32 * 64; i += 256) {
            int row = i >> 6, col = i & 63;
            if (row < fcnt)
                lds[row][col] =
                    (unsigned char)(m32[(size_t)(fb + row) * NX + n0 + col] != 0);
        }
    }
    __syncthreads();

    if (fcnt == 32) {
        for (int i = tid; i < 64 * 8; i += 256) {       // 8 dwords per n-row
            int nn = i >> 3, d = i & 7;
            unsigned w = (unsigned)lds[4 * d + 0][nn]
                       | ((unsigned)lds[4 * d + 1][nn] << 8)
                       | ((unsigned)lds[4 * d + 2][nn] << 16)
                       | ((unsigned)lds[4 * d + 3][nn] << 24);
            *(unsigned*)(mt + (size_t)(n0 + nn) * MT_STRIDE + fb + 4 * d) = w;
        }
    } else {
        for (int i = tid; i < 64 * 2; i += 256) {
            int nn = i >> 1, d = i & 1;
            unsigned w = (unsigned)lds[4 * d + 0][nn]
                       | ((unsigned)lds[4 * d + 1][nn] << 8)
                       | ((unsigned)lds[4 * d + 2][nn] << 16)
                       | ((unsigned)lds[4 * d + 3][nn] << 24);
            *(unsigned*)(mt + (size_t)(n0 + nn) * MT_STRIDE + fb + 4 * d) = w;
        }
    }
}

// ---------------------------------------------------------------------------
// VT -> fragment-ordered bf16 (A-frag per f-tile; k=(lane>>4)*8+j, f=lane&15).
// ---------------------------------------------------------------------------
__global__ __launch_bounds__(256) void vt_prep_kernel(
        const float* __restrict__ VT, unsigned short* __restrict__ VTfrag) {
    int i = blockIdx.x * 256 + threadIdx.x;
    if (i >= NFT * 512) return;
    int ft = i >> 9, r = i & 511, lane = r >> 3, j = r & 7;
    int k = (lane >> 4) * 8 + j;
    int f = ft * 16 + (lane & 15);
    unsigned short v = 0;
    if (k < NBASIS && f < NF) v = f2bf(VT[k * NF + f]);
    VTfrag[i] = v;
}

// ---------------------------------------------------------------------------
// Stage 3 via MFMA, LDS-transposed epilogue. R12 post-mortem: MFMA compute is
// ~free but the D-frag store pattern (4 x 64 B segments per instr, NT) halves
// HBM write efficiency -> ~330 us. Fix: per f-tile the 4 waves dump D frags
// into a 16x257 f32 LDS tile, sync, then store f-major: each store instr =
// 64 lanes x 4 B = 256 B contiguous (fill-kernel pattern, 6.8 TB/s), NT kept.
// Mask applied in the store phase (one dwordx4 of mt per thread per tile).
// ylds/lds2 union keeps LDS at 17 KB -> 8 blocks/CU.
// ---------------------------------------------------------------------------
__global__ __launch_bounds__(256) void project_mfma_kernel(
        const unsigned short* __restrict__ Abf,    // [240][NX] bf16
        const unsigned short* __restrict__ VTfrag, // [13][64][8] bf16
        const unsigned char*  __restrict__ mt,     // [NX][256] bytes
        float* __restrict__ out) {
    __shared__ __align__(16) unsigned char smem[16896];
    unsigned short (*ylds)[264] = (unsigned short (*)[264])smem;  // 32x264x2B
    float          (*lds2)[257] = (float (*)[257])smem;           // 16x257x4B

    const int tid = threadIdx.x;
    const int c   = blockIdx.y;
    const int n0  = blockIdx.x * 256;

    // Stage Y tile: rows b=0..29 from Abf, rows 30/31 zero (K padding).
    for (int i = tid; i < 32 * 32; i += 256) {
        int row = i >> 5, seg = i & 31;
        u32x4 v = (u32x4)(0u, 0u, 0u, 0u);
        if (row < NBASIS)
            v = *(const u32x4*)(Abf + ((size_t)(c * NBASIS + row)) * NX
                                + n0 + seg * 8);
        *(u32x4*)&ylds[row][seg * 8] = v;
    }
    __syncthreads();

    const int lane = tid & 63;
    const int wv   = tid >> 6;          // wave's 64-n sub-strip
    const int ksec = lane >> 4;
    const int fr   = lane & 15;

    // B-frags: 4 x 8 bf16 (frag fn covers n-local = wv*64 + fn*16 + fr).
    bf16x8 bfrag[4];
    #pragma unroll
    for (int fn = 0; fn < 4; ++fn) {
        #pragma unroll
        for (int j = 0; j < 8; ++j)
            bfrag[fn][j] = (short)ylds[ksec * 8 + j][wv * 64 + fn * 16 + fr];
    }
    __syncthreads();                    // ylds dead; smem becomes lds2

    const unsigned short* vtf  = VTfrag + lane * 8;
    const u32x4*          mrow = (const u32x4*)(mt + (size_t)(n0 + tid) * MT_STRIDE);
    float* outc = out + (size_t)c * NF * NX + n0 + tid;

    #pragma unroll 1
    for (int ft = 0; ft < NFT; ++ft) {
        bf16x8 afrag = *(const bf16x8*)(vtf + ft * 512);
        u32x4  md    = mrow[ft];        // mask bytes for f = ft*16 .. +15 at n0+tid

        #pragma unroll
        for (int fn = 0; fn < 4; ++fn) {
            f32x4 d = __builtin_amdgcn_mfma_f32_16x16x32_bf16(
                afrag, bfrag[fn], (f32x4)(0.f, 0.f, 0.f, 0.f), 0, 0, 0);
            int nl = wv * 64 + fn * 16 + fr;        // n-local
            #pragma unroll
            for (int r = 0; r < 4; ++r)
                lds2[ksec * 4 + r][nl] = d[r];       // f-local row, n-local col
        }
        __syncthreads();

        const int fvalid = NF - ft * 16 < 16 ? NF - ft * 16 : 16;  // 16 or 8
        #pragma unroll
        for (int fl = 0; fl < 16; ++fl) {
            if (fl >= fvalid) break;                // uniform guard
            unsigned mb = (md[fl >> 2] >> (8 * (fl & 3))) & 0xFFu;
            float o = mb ? lds2[fl][tid] : 0.0f;
            __builtin_nontemporal_store(o, outc + (size_t)(ft * 16 + fl) * NX);
        }
        __syncthreads();
    }
}

extern "C" void kernel_launch(void* const* d_in, const int* in_sizes, int n_in,
                              void* d_out, int out_size, void* d_ws, size_t ws_size,
                              hipStream_t stream) {
    const float* x    = (const float*)d_in[0];   // (30,256,256,2) f32
    const float* csm  = (const float*)d_in[1];   // (8,256,256,2) f32
    const float* VT   = (const float*)d_in[2];   // (30,200) f32
    const void*  mask = d_in[3];                 // (200,131072) bool/int
    float* out = (float*)d_out;                  // (8,200,131072) f32

    char* ws = (char*)d_ws;
    float*          A      = (float*)ws;                                  // 125.8 MB
    unsigned short* Abf    = (unsigned short*)(ws + ((size_t)128 << 20)); // 62.9 MB
    unsigned char*  mt     = (unsigned char*)(ws + ((size_t)192 << 20));  // 33.6 MB
    unsigned short* VTfrag = (unsigned short*)(ws + ((size_t)232 << 20)); // 13.3 KB

    vt_prep_kernel<<<(NFT * 512 + 255) / 256, 256, 0, stream>>>(VT, VTfrag);
    transpose_mask_kernel<<<dim3(NX / 64, 7), 256, 0, stream>>>(mask, mt);
    fft_rows_kernel<<<NIMG * 64, 256, 0, stream>>>(x, csm, A);
    fft_cols_kernel<<<NIMG * 16, 256, 0, stream>>>(A, Abf);
    project_mfma_kernel<<<dim3(NX / 256, NCH), 256, 0, stream>>>(Abf, VTfrag, mt, out);
}

// Round 14
// 392.718 us; speedup vs baseline: 1.4933x; 1.0802x over previous
//
#include <hip/hip_runtime.h>

#define NCH    8
#define NBASIS 30
#define NXS    256
#define NF     200
#define NX     (NXS*NXS*2)      // 131072
#define NIMG   (NCH*NBASIS)     // 240
#define NFT    13               // f-tiles of 16 (13*16 = 208 >= 200)

typedef float    f32x4  __attribute__((ext_vector_type(4)));
typedef unsigned u32x4  __attribute__((ext_vector_type(4)));
typedef short    bf16x8 __attribute__((ext_vector_type(8)));

__device__ __forceinline__ int bitrev8(int v) {
    return (int)(__builtin_bitreverse32((unsigned)v) >> 24);
}

__device__ __forceinline__ unsigned short f2bf(float f) {   // RNE f32->bf16
    unsigned u = __float_as_uint(f);
    return (unsigned short)((u + 0x7FFFu + ((u >> 16) & 1u)) >> 16);
}

// ---------------------------------------------------------------------------
// Pass 1: w = (x * csm) * (-1)^(row+col); FFT along the contiguous (col) axis.
// Output bf16 (Amid) — halves the pass-1 writeback (126 -> 63 MB).
// ---------------------------------------------------------------------------
__global__ __launch_bounds__(256) void fft_rows_kernel(
        const float* __restrict__ x, const float* __restrict__ csm,
        unsigned short* __restrict__ Amid) {
    __shared__ float ldsRe[4][256];
    __shared__ float ldsIm[4][256];
    __shared__ float twRe[128], twIm[128];

    const int tid   = threadIdx.x;
    const int slice = tid >> 6;
    const int lane  = tid & 63;
    const int blk   = blockIdx.x;       // m*64 + rowTile
    const int m     = blk >> 6;
    const int row   = ((blk & 63) << 2) + slice;
    const int c     = m / NBASIS;
    const int b     = m - c * NBASIS;

    if (tid < 128) {
        float a = (float)tid * (1.0f / 128.0f);   // theta = pi * a
        twRe[tid] =  cospif(a);
        twIm[tid] = -sinpif(a);
    }

    const float* xr = x   + ((size_t)(b * NXS + row) * NXS) * 2;
    const float* cr = csm + ((size_t)(c * NXS + row) * NXS) * 2;
    #pragma unroll
    for (int j = 0; j < 4; ++j) {
        int col = lane + 64 * j;
        float2 xv = *(const float2*)(xr + col * 2);
        float2 cv = *(const float2*)(cr + col * 2);
        float s = ((row + col) & 1) ? -1.0f : 1.0f;
        ldsRe[slice][col] = s * (xv.x * cv.x - xv.y * cv.y);
        ldsIm[slice][col] = s * (xv.x * cv.y + xv.y * cv.x);
    }
    __syncthreads();

    #pragma unroll
    for (int half = 128; half >= 1; half >>= 1) {
        #pragma unroll
        for (int qq = 0; qq < 2; ++qq) {
            int q  = lane + 64 * qq;
            int g  = q / half;
            int j  = q - g * half;
            int i0 = g * 2 * half + j;
            int i1 = i0 + half;
            float ar = ldsRe[slice][i0], ai = ldsIm[slice][i0];
            float br = ldsRe[slice][i1], bi = ldsIm[slice][i1];
            ldsRe[slice][i0] = ar + br;
            ldsIm[slice][i0] = ai + bi;
            float dr = ar - br, di = ai - bi;
            int k = j * (128 / half);
            float wr = twRe[k], wi = twIm[k];
            ldsRe[slice][i1] = dr * wr - di * wi;
            ldsIm[slice][i1] = dr * wi + di * wr;
        }
        __syncthreads();
    }

    unsigned short* outp = Amid + (size_t)m * NX + (size_t)row * NXS * 2;
    #pragma unroll
    for (int j = 0; j < 4; ++j) {
        int k  = lane + 64 * j;
        int rk = bitrev8(k);
        unsigned pack = (unsigned)f2bf(ldsRe[slice][rk])
                      | ((unsigned)f2bf(ldsIm[slice][rk]) << 16);
        *(unsigned*)(outp + k * 2) = pack;
    }
}

// ---------------------------------------------------------------------------
// Pass 2: FFT along the row axis; bf16 in (Amid), bf16 out (Abf).
// ---------------------------------------------------------------------------
#define CTILE 16
__global__ __launch_bounds__(256) void fft_cols_kernel(
        const unsigned short* __restrict__ Amid, unsigned short* __restrict__ Abf) {
    __shared__ float ldsRe[CTILE][257];
    __shared__ float ldsIm[CTILE][257];
    __shared__ float twRe[128], twIm[128];

    const int tid = threadIdx.x;
    const int blk = blockIdx.x;
    const int m   = blk >> 4;             // 16 tiles per image
    const int k0  = (blk & 15) * CTILE;

    if (tid < 128) {
        float a = (float)tid * (1.0f / 128.0f);
        twRe[tid] =  cospif(a);
        twIm[tid] = -sinpif(a);
    }

    const unsigned short* base = Amid + (size_t)m * NX;
    #pragma unroll
    for (int it = 0; it < 16; ++it) {
        int li = it * 256 + tid;
        int r  = li >> 4;
        int cc = li & 15;
        unsigned v = *(const unsigned*)(base + ((size_t)r * NXS + k0 + cc) * 2);
        ldsRe[cc][r] = __uint_as_float(v << 16);
        ldsIm[cc][r] = __uint_as_float(v & 0xFFFF0000u);
    }
    __syncthreads();

    const int slice = tid >> 6;
    const int lane  = tid & 63;

    #pragma unroll
    for (int half = 128; half >= 1; half >>= 1) {
        #pragma unroll
        for (int ci = 0; ci < 4; ++ci) {
            int col = slice * 4 + ci;
            #pragma unroll
            for (int qq = 0; qq < 2; ++qq) {
                int q  = lane + 64 * qq;
                int g  = q / half;
                int j  = q - g * half;
                int i0 = g * 2 * half + j;
                int i1 = i0 + half;
                float ar = ldsRe[col][i0], ai = ldsIm[col][i0];
                float br = ldsRe[col][i1], bi = ldsIm[col][i1];
                ldsRe[col][i0] = ar + br;
                ldsIm[col][i0] = ai + bi;
                float dr = ar - br, di = ai - bi;
                int k = j * (128 / half);
                float wr = twRe[k], wi = twIm[k];
                ldsRe[col][i1] = dr * wr - di * wi;
                ldsIm[col][i1] = dr * wi + di * wr;
            }
        }
        __syncthreads();
    }

    unsigned short* obase = Abf + (size_t)m * NX;
    #pragma unroll
    for (int it = 0; it < 16; ++it) {
        int li = it * 256 + tid;
        int ky = li >> 4;
        int cc = li & 15;
        int kx = k0 + cc;
        int rk = bitrev8(ky);
        float s = (((ky + kx) & 1) ? -1.0f : 1.0f) * (1.0f / 256.0f);
        unsigned pack = ((unsigned)f2bf(s * ldsIm[cc][rk]) << 16)
                      |  (unsigned)f2bf(s * ldsRe[cc][rk]);
        *(unsigned*)(obase + ((size_t)ky * NXS + kx) * 2) = pack;
    }
}

// ---------------------------------------------------------------------------
// VT -> fragment-ordered bf16 (k=(lane>>4)*8+j, f=lane&15, zero-padded).
// ---------------------------------------------------------------------------
__global__ __launch_bounds__(256) void vt_prep_kernel(
        const float* __restrict__ VT, unsigned short* __restrict__ VTfrag) {
    int i = blockIdx.x * 256 + threadIdx.x;
    if (i >= NFT * 512) return;
    int ft = i >> 9, r = i & 511, lane = r >> 3, j = r & 7;
    int k = (lane >> 4) * 8 + j;
    int f = ft * 16 + (lane & 15);
    unsigned short v = 0;
    if (k < NBASIS && f < NF) v = f2bf(VT[k * NF + f]);
    VTfrag[i] = v;
}

// ---------------------------------------------------------------------------
// Stage 3, barrier-free. R13 post-mortem: 26 __syncthreads in the hot loop
// each forced a vmcnt(0) drain of NT stores (HBM-ack convoy, R10 redux).
// This version swaps MFMA operands: D = mfma(Yfrag, VTfrag) has row = n
// (4 CONSECUTIVE n per lane), col = f = lane&15. Each wave round-trips its
// private 16f x 64n tile through its own LDS region (in-order per-wave DS,
// lgkmcnt(0) + wave_barrier only — NO block barriers), then NT-stores
// dwordx4 (256 B contiguous per 16-lane group). Mask: f is fixed per lane,
// so one dword of ORIGINAL maskT[f][n..n+3] per fragment — transpose kernel
// deleted. ylds/ldsW union = 4.75 KB/wave -> 19 KB/block -> 8 blocks/CU.
// ---------------------------------------------------------------------------
__global__ __launch_bounds__(256) void project_mfma_kernel(
        const unsigned short* __restrict__ Abf,    // [240][NX] bf16
        const unsigned short* __restrict__ VTfrag, // [13][64][8] bf16
        const void*           __restrict__ maskT,  // [200][NX] byte or int32
        float* __restrict__ out) {
    __shared__ __align__(16) unsigned char smem[4][4864];

    const int tid  = threadIdx.x;
    const int wv   = tid >> 6;
    const int lane = tid & 63;
    const int ksec = lane >> 4;
    const int fr   = lane & 15;
    const int c    = blockIdx.y;
    const int n0w  = blockIdx.x * 256 + wv * 64;

    // Detect mask storage: bool-as-byte vs int32 (uniform, scalar loads).
    const unsigned* mwd = (const unsigned*)maskT;
    bool byteMode = false;
    #pragma unroll
    for (int i = 0; i < 32; ++i) byteMode |= (mwd[i] > 1u);

    unsigned short (*ylds)[72] = (unsigned short (*)[72])smem[wv]; // 32x72 bf16
    float          (*ldsW)[68] = (float (*)[68])smem[wv];          // 16x68 f32

    // Stage this wave's 64-n Y strip (rows 0..29; 30/31 zero K-padding).
    {
        const unsigned short* src = Abf + (size_t)c * NBASIS * NX + n0w;
        #pragma unroll
        for (int i = 0; i < 4; ++i) {
            int idx = lane + 64 * i;            // 0..255
            int row = idx >> 3, seg = idx & 7;
            u32x4 v = (u32x4)(0u, 0u, 0u, 0u);
            if (row < NBASIS)
                v = *(const u32x4*)(src + (size_t)row * NX + seg * 8);
            *(u32x4*)&ylds[row][seg * 8] = v;
        }
    }
    __builtin_amdgcn_wave_barrier();
    asm volatile("s_waitcnt lgkmcnt(0)" ::: "memory");
    __builtin_amdgcn_sched_barrier(0);

    // Gather A-frags (Y): yfrag[fn][j] = Y[k=ksec*8+j][n_local=fn*16+fr].
    bf16x8 yfrag[4];
    #pragma unroll
    for (int fn = 0; fn < 4; ++fn) {
        #pragma unroll
        for (int j = 0; j < 8; ++j)
            yfrag[fn][j] = (short)ylds[ksec * 8 + j][fn * 16 + fr];
    }
    __builtin_amdgcn_wave_barrier();
    asm volatile("s_waitcnt lgkmcnt(0)" ::: "memory");
    __builtin_amdgcn_sched_barrier(0);           // ylds dead; region becomes ldsW

    const unsigned short* vtp = VTfrag + lane * 8;
    float* outc = out + (size_t)c * NF * NX;

    #pragma unroll 1
    for (int ft = 0; ft < NFT; ++ft) {
        bf16x8 vt = *(const bf16x8*)(vtp + ft * 512);

        // Mask: this lane's f is ft*16+fr; 4 consecutive n per fragment.
        const int  f_l = ft * 16 + fr;
        const bool fok = f_l < NF;
        unsigned md[4];
        if (byteMode) {
            const unsigned char* mb = (const unsigned char*)maskT
                + (size_t)f_l * NX + n0w + ksec * 4;
            #pragma unroll
            for (int fn = 0; fn < 4; ++fn)
                md[fn] = fok ? *(const unsigned*)(mb + fn * 16) : 0u;
        } else {
            const int* mi = (const int*)maskT + (size_t)f_l * NX + n0w + ksec * 4;
            #pragma unroll
            for (int fn = 0; fn < 4; ++fn) {
                unsigned m = 0;
                if (fok) {
                    u32x4 v = *(const u32x4*)(mi + fn * 16);
                    m = (v.x ? 1u : 0u) | (v.y ? 0x100u : 0u)
                      | (v.z ? 0x10000u : 0u) | (v.w ? 0x1000000u : 0u);
                }
                md[fn] = m;
            }
        }

        // D2[n][f]: lane holds out[f=ft*16+fr][n0w + fn*16 + ksec*4 + reg].
        #pragma unroll
        for (int fn = 0; fn < 4; ++fn) {
            f32x4 d = __builtin_amdgcn_mfma_f32_16x16x32_bf16(
                yfrag[fn], vt, (f32x4)(0.f, 0.f, 0.f, 0.f), 0, 0, 0);
            f32x4 o;
            #pragma unroll
            for (int r = 0; r < 4; ++r)
                o[r] = ((md[fn] >> (8 * r)) & 0xFFu) ? d[r] : 0.0f;
            *(f32x4*)&ldsW[fr][fn * 16 + ksec * 4] = o;   // row f_local=fr
        }
        __builtin_amdgcn_wave_barrier();
        asm volatile("s_waitcnt lgkmcnt(0)" ::: "memory");
        __builtin_amdgcn_sched_barrier(0);

        // f-major drain: 16 lanes x 16 B = 256 B contiguous per f-row.
        #pragma unroll
        for (int rl = 0; rl < 4; ++rl) {
            int f_local = rl * 4 + ksec;
            int f = ft * 16 + f_local;
            f32x4 v = *(const f32x4*)&ldsW[f_local][fr * 4];
            if (f < NF)
                __builtin_nontemporal_store(v,
                    (f32x4*)(outc + (size_t)f * NX + n0w + fr * 4));
        }
        __builtin_amdgcn_wave_barrier();
    }
}

extern "C" void kernel_launch(void* const* d_in, const int* in_sizes, int n_in,
                              void* d_out, int out_size, void* d_ws, size_t ws_size,
                              hipStream_t stream) {
    const float* x    = (const float*)d_in[0];   // (30,256,256,2) f32
    const float* csm  = (const float*)d_in[1];   // (8,256,256,2) f32
    const float* VT   = (const float*)d_in[2];   // (30,200) f32
    const void*  mask = d_in[3];                 // (200,131072) bool/int
    float* out = (float*)d_out;                  // (8,200,131072) f32

    char* ws = (char*)d_ws;
    unsigned short* Amid   = (unsigned short*)ws;                         // 62.9 MB
    unsigned short* Abf    = (unsigned short*)(ws + ((size_t)64 << 20));  // 62.9 MB
    unsigned short* VTfrag = (unsigned short*)(ws + ((size_t)128 << 20)); // 13.3 KB

    vt_prep_kernel<<<(NFT * 512 + 255) / 256, 256, 0, stream>>>(VT, VTfrag);
    fft_rows_kernel<<<NIMG * 64, 256, 0, stream>>>(x, csm, Amid);
    fft_cols_kernel<<<NIMG * 16, 256, 0, stream>>>(Amid, Abf);
    project_mfma_kernel<<<dim3(NX / 256, NCH), 256, 0, stream>>>(Abf, VTfrag, mask, out);
}

// Round 15
// 326.954 us; speedup vs baseline: 1.7937x; 1.2011x over previous
//
#include <hip/hip_runtime.h>

#define NCH    8
#define NBASIS 30
#define NXS    256
#define NF     200
#define NX     (NXS*NXS*2)      // 131072
#define NIMG   (NCH*NBASIS)     // 240
#define NFT    13               // f-tiles of 16 (13*16 = 208 >= 200)
#define CPB    4                // channels per block (stage-3)

typedef float    f32x4  __attribute__((ext_vector_type(4)));
typedef unsigned u32x4  __attribute__((ext_vector_type(4)));
typedef short    bf16x8 __attribute__((ext_vector_type(8)));

__device__ __forceinline__ int bitrev8(int v) {
    return (int)(__builtin_bitreverse32((unsigned)v) >> 24);
}

__device__ __forceinline__ unsigned short f2bf(float f) {   // RNE f32->bf16
    unsigned u = __float_as_uint(f);
    return (unsigned short)((u + 0x7FFFu + ((u >> 16) & 1u)) >> 16);
}

// ---------------------------------------------------------------------------
// Pass 1: w = (x * csm) * (-1)^(row+col); FFT along the contiguous (col) axis.
// Output bf16 (Amid).
// ---------------------------------------------------------------------------
__global__ __launch_bounds__(256) void fft_rows_kernel(
        const float* __restrict__ x, const float* __restrict__ csm,
        unsigned short* __restrict__ Amid) {
    __shared__ float ldsRe[4][256];
    __shared__ float ldsIm[4][256];
    __shared__ float twRe[128], twIm[128];

    const int tid   = threadIdx.x;
    const int slice = tid >> 6;
    const int lane  = tid & 63;
    const int blk   = blockIdx.x;       // m*64 + rowTile
    const int m     = blk >> 6;
    const int row   = ((blk & 63) << 2) + slice;
    const int c     = m / NBASIS;
    const int b     = m - c * NBASIS;

    if (tid < 128) {
        float a = (float)tid * (1.0f / 128.0f);   // theta = pi * a
        twRe[tid] =  cospif(a);
        twIm[tid] = -sinpif(a);
    }

    const float* xr = x   + ((size_t)(b * NXS + row) * NXS) * 2;
    const float* cr = csm + ((size_t)(c * NXS + row) * NXS) * 2;
    #pragma unroll
    for (int j = 0; j < 4; ++j) {
        int col = lane + 64 * j;
        float2 xv = *(const float2*)(xr + col * 2);
        float2 cv = *(const float2*)(cr + col * 2);
        float s = ((row + col) & 1) ? -1.0f : 1.0f;
        ldsRe[slice][col] = s * (xv.x * cv.x - xv.y * cv.y);
        ldsIm[slice][col] = s * (xv.x * cv.y + xv.y * cv.x);
    }
    __syncthreads();

    #pragma unroll
    for (int half = 128; half >= 1; half >>= 1) {
        #pragma unroll
        for (int qq = 0; qq < 2; ++qq) {
            int q  = lane + 64 * qq;
            int g  = q / half;
            int j  = q - g * half;
            int i0 = g * 2 * half + j;
            int i1 = i0 + half;
            float ar = ldsRe[slice][i0], ai = ldsIm[slice][i0];
            float br = ldsRe[slice][i1], bi = ldsIm[slice][i1];
            ldsRe[slice][i0] = ar + br;
            ldsIm[slice][i0] = ai + bi;
            float dr = ar - br, di = ai - bi;
            int k = j * (128 / half);
            float wr = twRe[k], wi = twIm[k];
            ldsRe[slice][i1] = dr * wr - di * wi;
            ldsIm[slice][i1] = dr * wi + di * wr;
        }
        __syncthreads();
    }

    unsigned short* outp = Amid + (size_t)m * NX + (size_t)row * NXS * 2;
    #pragma unroll
    for (int j = 0; j < 4; ++j) {
        int k  = lane + 64 * j;
        int rk = bitrev8(k);
        unsigned pack = (unsigned)f2bf(ldsRe[slice][rk])
                      | ((unsigned)f2bf(ldsIm[slice][rk]) << 16);
        *(unsigned*)(outp + k * 2) = pack;
    }
}

// ---------------------------------------------------------------------------
// Pass 2: FFT along the row axis; bf16 in (Amid), bf16 out (Abf).
// ---------------------------------------------------------------------------
#define CTILE 16
__global__ __launch_bounds__(256) void fft_cols_kernel(
        const unsigned short* __restrict__ Amid, unsigned short* __restrict__ Abf) {
    __shared__ float ldsRe[CTILE][257];
    __shared__ float ldsIm[CTILE][257];
    __shared__ float twRe[128], twIm[128];

    const int tid = threadIdx.x;
    const int blk = blockIdx.x;
    const int m   = blk >> 4;             // 16 tiles per image
    const int k0  = (blk & 15) * CTILE;

    if (tid < 128) {
        float a = (float)tid * (1.0f / 128.0f);
        twRe[tid] =  cospif(a);
        twIm[tid] = -sinpif(a);
    }

    const unsigned short* base = Amid + (size_t)m * NX;
    #pragma unroll
    for (int it = 0; it < 16; ++it) {
        int li = it * 256 + tid;
        int r  = li >> 4;
        int cc = li & 15;
        unsigned v = *(const unsigned*)(base + ((size_t)r * NXS + k0 + cc) * 2);
        ldsRe[cc][r] = __uint_as_float(v << 16);
        ldsIm[cc][r] = __uint_as_float(v & 0xFFFF0000u);
    }
    __syncthreads();

    const int slice = tid >> 6;
    const int lane  = tid & 63;

    #pragma unroll
    for (int half = 128; half >= 1; half >>= 1) {
        #pragma unroll
        for (int ci = 0; ci < 4; ++ci) {
            int col = slice * 4 + ci;
            #pragma unroll
            for (int qq = 0; qq < 2; ++qq) {
                int q  = lane + 64 * qq;
                int g  = q / half;
                int j  = q - g * half;
                int i0 = g * 2 * half + j;
                int i1 = i0 + half;
                float ar = ldsRe[col][i0], ai = ldsIm[col][i0];
                float br = ldsRe[col][i1], bi = ldsIm[col][i1];
                ldsRe[col][i0] = ar + br;
                ldsIm[col][i0] = ai + bi;
                float dr = ar - br, di = ai - bi;
                int k = j * (128 / half);
                float wr = twRe[k], wi = twIm[k];
                ldsRe[col][i1] = dr * wr - di * wi;
                ldsIm[col][i1] = dr * wi + di * wr;
            }
        }
        __syncthreads();
    }

    unsigned short* obase = Abf + (size_t)m * NX;
    #pragma unroll
    for (int it = 0; it < 16; ++it) {
        int li = it * 256 + tid;
        int ky = li >> 4;
        int cc = li & 15;
        int kx = k0 + cc;
        int rk = bitrev8(ky);
        float s = (((ky + kx) & 1) ? -1.0f : 1.0f) * (1.0f / 256.0f);
        unsigned pack = ((unsigned)f2bf(s * ldsIm[cc][rk]) << 16)
                      |  (unsigned)f2bf(s * ldsRe[cc][rk]);
        *(unsigned*)(obase + ((size_t)ky * NXS + kx) * 2) = pack;
    }
}

// ---------------------------------------------------------------------------
// VT -> fragment-ordered bf16 (k=(lane>>4)*8+j, f=lane&15, zero-padded).
// ---------------------------------------------------------------------------
__global__ __launch_bounds__(256) void vt_prep_kernel(
        const float* __restrict__ VT, unsigned short* __restrict__ VTfrag) {
    int i = blockIdx.x * 256 + threadIdx.x;
    if (i >= NFT * 512) return;
    int ft = i >> 9, r = i & 511, lane = r >> 3, j = r & 7;
    int k = (lane >> 4) * 8 + j;
    int f = ft * 16 + (lane & 15);
    unsigned short v = 0;
    if (k < NBASIS && f < NF) v = f2bf(VT[k * NF + f]);
    VTfrag[i] = v;
}

// ---------------------------------------------------------------------------
// Stage 3. R14 post-mortem: every structure lands 300-370 us because VMEM
// loads (mask/VT/Y) issued after NT stores force in-order vmcnt drains of the
// HBM store queue (~65 drains/wave). This version has ZERO vmem loads inside
// the store stream: mask pre-packed to 7 bit-VGPRs at wave start (ft loop
// fully unrolled -> static indices, rule #20), VTfrag copied to LDS once per
// block (reads are lgkm-only), c-loop (CPB=4) inside the block amortizes both
// and cuts mask HBM traffic 208->52 MB. Drains/wave: 4 (one Y re-stage per c).
// ---------------------------------------------------------------------------
__global__ __launch_bounds__(256) void project_mfma_kernel(
        const unsigned short* __restrict__ Abf,    // [240][NX] bf16
        const unsigned short* __restrict__ VTfrag, // [13][64][8] bf16
        const void*           __restrict__ maskT,  // [200][NX] byte or int32
        float* __restrict__ out) {
    __shared__ __align__(16) unsigned char smem[4][4864];      // 19456 B
    __shared__ __align__(16) unsigned short vtlds[NFT * 512];  // 13312 B

    const int tid  = threadIdx.x;
    const int wv   = tid >> 6;
    const int lane = tid & 63;
    const int ksec = lane >> 4;
    const int fr   = lane & 15;
    const int c0   = blockIdx.y * CPB;
    const int n0w  = blockIdx.x * 256 + wv * 64;

    // Copy VTfrag to LDS (one block barrier, before any NT store).
    {
        const u32x4* src = (const u32x4*)VTfrag;
        u32x4*       dst = (u32x4*)vtlds;
        for (int i = tid; i < NFT * 512 / 8; i += 256) dst[i] = src[i];
    }

    // Detect mask storage: bool-as-byte vs int32 (uniform, scalar loads).
    const unsigned* mwd = (const unsigned*)maskT;
    bool byteMode = false;
    #pragma unroll
    for (int i = 0; i < 32; ++i) byteMode |= (mwd[i] > 1u);

    // Bit-pack this lane's mask: bit p = ft*16 + fn*4 + r  (f=ft*16+fr,
    // n = n0w + fn*16 + ksec*4 + r). All loads happen BEFORE any store.
    unsigned mbits[7] = {0u, 0u, 0u, 0u, 0u, 0u, 0u};
    if (byteMode) {
        const unsigned char* mb = (const unsigned char*)maskT + n0w + ksec * 4;
        #pragma unroll
        for (int ft = 0; ft < NFT; ++ft) {
            const int f_l = ft * 16 + fr;
            #pragma unroll
            for (int fn = 0; fn < 4; ++fn) {
                unsigned w = (f_l < NF)
                    ? *(const unsigned*)(mb + (size_t)f_l * NX + fn * 16) : 0u;
                unsigned nib = (w | (w >> 7) | (w >> 14) | (w >> 21)) & 0xFu;
                const int p = ft * 16 + fn * 4;
                mbits[p >> 5] |= nib << (p & 31);
            }
        }
    } else {
        const int* mi = (const int*)maskT + n0w + ksec * 4;
        #pragma unroll
        for (int ft = 0; ft < NFT; ++ft) {
            const int f_l = ft * 16 + fr;
            #pragma unroll
            for (int fn = 0; fn < 4; ++fn) {
                unsigned nib = 0u;
                if (f_l < NF) {
                    u32x4 v = *(const u32x4*)(mi + (size_t)f_l * NX + fn * 16);
                    nib = (v.x ? 1u : 0u) | (v.y ? 2u : 0u)
                        | (v.z ? 4u : 0u) | (v.w ? 8u : 0u);
                }
                const int p = ft * 16 + fn * 4;
                mbits[p >> 5] |= nib << (p & 31);
            }
        }
    }

    unsigned short (*ylds)[72] = (unsigned short (*)[72])smem[wv]; // 32x72 bf16
    float          (*ldsW)[68] = (float (*)[68])smem[wv];          // 16x68 f32

    __syncthreads();     // vtlds ready (also orders first ylds use)

    #pragma unroll 1
    for (int cc = 0; cc < CPB; ++cc) {
        const int c = c0 + cc;

        // Stage this wave's 64-n Y strip for channel c (rows 30/31 zero).
        {
            const unsigned short* src = Abf + (size_t)c * NBASIS * NX + n0w;
            #pragma unroll
            for (int i = 0; i < 4; ++i) {
                int idx = lane + 64 * i;            // 0..255
                int row = idx >> 3, seg = idx & 7;
                u32x4 v = (u32x4)(0u, 0u, 0u, 0u);
                if (row < NBASIS)
                    v = *(const u32x4*)(src + (size_t)row * NX + seg * 8);
                *(u32x4*)&ylds[row][seg * 8] = v;
            }
        }
        __builtin_amdgcn_wave_barrier();
        asm volatile("s_waitcnt lgkmcnt(0)" ::: "memory");
        __builtin_amdgcn_sched_barrier(0);

        // Gather A-frags: yfrag[fn][j] = Y[k=ksec*8+j][n_local=fn*16+fr].
        bf16x8 yfrag[4];
        #pragma unroll
        for (int fn = 0; fn < 4; ++fn) {
            #pragma unroll
            for (int j = 0; j < 8; ++j)
                yfrag[fn][j] = (short)ylds[ksec * 8 + j][fn * 16 + fr];
        }
        __builtin_amdgcn_wave_barrier();
        asm volatile("s_waitcnt lgkmcnt(0)" ::: "memory");
        __builtin_amdgcn_sched_barrier(0);       // ylds dead; region -> ldsW

        float* outc = out + (size_t)c * NF * NX;

        #pragma unroll
        for (int ft = 0; ft < NFT; ++ft) {
            bf16x8 vt = *(const bf16x8*)&vtlds[ft * 512 + lane * 8]; // lgkm only

            #pragma unroll
            for (int fn = 0; fn < 4; ++fn) {
                const int p = ft * 16 + fn * 4;
                const unsigned nib = (mbits[p >> 5] >> (p & 31)) & 0xFu;
                f32x4 d = __builtin_amdgcn_mfma_f32_16x16x32_bf16(
                    yfrag[fn], vt, (f32x4)(0.f, 0.f, 0.f, 0.f), 0, 0, 0);
                f32x4 o;
                #pragma unroll
                for (int r = 0; r < 4; ++r)
                    o[r] = (nib & (1u << r)) ? d[r] : 0.0f;
                *(f32x4*)&ldsW[fr][fn * 16 + ksec * 4] = o;
            }
            __builtin_amdgcn_wave_barrier();
            asm volatile("s_waitcnt lgkmcnt(0)" ::: "memory");
            __builtin_amdgcn_sched_barrier(0);

            // f-major drain: 16 lanes x 16 B = 256 B contiguous per f-row.
            #pragma unroll
            for (int rl = 0; rl < 4; ++rl) {
                int f_local = rl * 4 + ksec;
                int f = ft * 16 + f_local;
                f32x4 v = *(const f32x4*)&ldsW[f_local][fr * 4];
                if (f < NF)
                    __builtin_nontemporal_store(v,
                        (f32x4*)(outc + (size_t)f * NX + n0w + fr * 4));
            }
            __builtin_amdgcn_wave_barrier();
        }
    }
}

extern "C" void kernel_launch(void* const* d_in, const int* in_sizes, int n_in,
                              void* d_out, int out_size, void* d_ws, size_t ws_size,
                              hipStream_t stream) {
    const float* x    = (const float*)d_in[0];   // (30,256,256,2) f32
    const float* csm  = (const float*)d_in[1];   // (8,256,256,2) f32
    const float* VT   = (const float*)d_in[2];   // (30,200) f32
    const void*  mask = d_in[3];                 // (200,131072) bool/int
    float* out = (float*)d_out;                  // (8,200,131072) f32

    char* ws = (char*)d_ws;
    unsigned short* Amid   = (unsigned short*)ws;                         // 62.9 MB
    unsigned short* Abf    = (unsigned short*)(ws + ((size_t)64 << 20));  // 62.9 MB
    unsigned short* VTfrag = (unsigned short*)(ws + ((size_t)128 << 20)); // 13.3 KB

    vt_prep_kernel<<<(NFT * 512 + 255) / 256, 256, 0, stream>>>(VT, VTfrag);
    fft_rows_kernel<<<NIMG * 64, 256, 0, stream>>>(x, csm, Amid);
    fft_cols_kernel<<<NIMG * 16, 256, 0, stream>>>(Amid, Abf);
    project_mfma_kernel<<<dim3(NX / 256, NCH / CPB), 256, 0, stream>>>(
        Abf, VTfrag, mask, out);
}

// Round 16
// 326.167 us; speedup vs baseline: 1.7980x; 1.0024x over previous
//
#include <hip/hip_runtime.h>

#define NCH    8
#define NBASIS 30
#define NXS    256
#define NF     200
#define NX     (NXS*NXS*2)      // 131072
#define NIMG   (NCH*NBASIS)     // 240
#define NFT    13               // f-tiles of 16 (13*16 = 208 >= 200)
#define CPB    4                // channels per block (stage-3)

typedef float    f32x4  __attribute__((ext_vector_type(4)));
typedef unsigned u32x4  __attribute__((ext_vector_type(4)));
typedef short    bf16x8 __attribute__((ext_vector_type(8)));

__device__ __forceinline__ int bitrev8(int v) {
    return (int)(__builtin_bitreverse32((unsigned)v) >> 24);
}

__device__ __forceinline__ unsigned short f2bf(float f) {   // RNE f32->bf16
    unsigned u = __float_as_uint(f);
    return (unsigned short)((u + 0x7FFFu + ((u >> 16) & 1u)) >> 16);
}

// ---------------------------------------------------------------------------
// Pass 1: w = (x * csm) * (-1)^(row+col); FFT along the contiguous (col) axis.
// Output bf16 (Amid).
// ---------------------------------------------------------------------------
__global__ __launch_bounds__(256) void fft_rows_kernel(
        const float* __restrict__ x, const float* __restrict__ csm,
        unsigned short* __restrict__ Amid) {
    __shared__ float ldsRe[4][256];
    __shared__ float ldsIm[4][256];
    __shared__ float twRe[128], twIm[128];

    const int tid   = threadIdx.x;
    const int slice = tid >> 6;
    const int lane  = tid & 63;
    const int blk   = blockIdx.x;       // m*64 + rowTile
    const int m     = blk >> 6;
    const int row   = ((blk & 63) << 2) + slice;
    const int c     = m / NBASIS;
    const int b     = m - c * NBASIS;

    if (tid < 128) {
        float a = (float)tid * (1.0f / 128.0f);   // theta = pi * a
        twRe[tid] =  cospif(a);
        twIm[tid] = -sinpif(a);
    }

    const float* xr = x   + ((size_t)(b * NXS + row) * NXS) * 2;
    const float* cr = csm + ((size_t)(c * NXS + row) * NXS) * 2;
    #pragma unroll
    for (int j = 0; j < 4; ++j) {
        int col = lane + 64 * j;
        float2 xv = *(const float2*)(xr + col * 2);
        float2 cv = *(const float2*)(cr + col * 2);
        float s = ((row + col) & 1) ? -1.0f : 1.0f;
        ldsRe[slice][col] = s * (xv.x * cv.x - xv.y * cv.y);
        ldsIm[slice][col] = s * (xv.x * cv.y + xv.y * cv.x);
    }
    __syncthreads();

    #pragma unroll
    for (int half = 128; half >= 1; half >>= 1) {
        #pragma unroll
        for (int qq = 0; qq < 2; ++qq) {
            int q  = lane + 64 * qq;
            int g  = q / half;
            int j  = q - g * half;
            int i0 = g * 2 * half + j;
            int i1 = i0 + half;
            float ar = ldsRe[slice][i0], ai = ldsIm[slice][i0];
            float br = ldsRe[slice][i1], bi = ldsIm[slice][i1];
            ldsRe[slice][i0] = ar + br;
            ldsIm[slice][i0] = ai + bi;
            float dr = ar - br, di = ai - bi;
            int k = j * (128 / half);
            float wr = twRe[k], wi = twIm[k];
            ldsRe[slice][i1] = dr * wr - di * wi;
            ldsIm[slice][i1] = dr * wi + di * wr;
        }
        __syncthreads();
    }

    unsigned short* outp = Amid + (size_t)m * NX + (size_t)row * NXS * 2;
    #pragma unroll
    for (int j = 0; j < 4; ++j) {
        int k  = lane + 64 * j;
        int rk = bitrev8(k);
        unsigned pack = (unsigned)f2bf(ldsRe[slice][rk])
                      | ((unsigned)f2bf(ldsIm[slice][rk]) << 16);
        *(unsigned*)(outp + k * 2) = pack;
    }
}

// ---------------------------------------------------------------------------
// Pass 2: FFT along the row axis; bf16 in (Amid), bf16 out (Abf).
// ---------------------------------------------------------------------------
#define CTILE 16
__global__ __launch_bounds__(256) void fft_cols_kernel(
        const unsigned short* __restrict__ Amid, unsigned short* __restrict__ Abf) {
    __shared__ float ldsRe[CTILE][257];
    __shared__ float ldsIm[CTILE][257];
    __shared__ float twRe[128], twIm[128];

    const int tid = threadIdx.x;
    const int blk = blockIdx.x;
    const int m   = blk >> 4;             // 16 tiles per image
    const int k0  = (blk & 15) * CTILE;

    if (tid < 128) {
        float a = (float)tid * (1.0f / 128.0f);
        twRe[tid] =  cospif(a);
        twIm[tid] = -sinpif(a);
    }

    const unsigned short* base = Amid + (size_t)m * NX;
    #pragma unroll
    for (int it = 0; it < 16; ++it) {
        int li = it * 256 + tid;
        int r  = li >> 4;
        int cc = li & 15;
        unsigned v = *(const unsigned*)(base + ((size_t)r * NXS + k0 + cc) * 2);
        ldsRe[cc][r] = __uint_as_float(v << 16);
        ldsIm[cc][r] = __uint_as_float(v & 0xFFFF0000u);
    }
    __syncthreads();

    const int slice = tid >> 6;
    const int lane  = tid & 63;

    #pragma unroll
    for (int half = 128; half >= 1; half >>= 1) {
        #pragma unroll
        for (int ci = 0; ci < 4; ++ci) {
            int col = slice * 4 + ci;
            #pragma unroll
            for (int qq = 0; qq < 2; ++qq) {
                int q  = lane + 64 * qq;
                int g  = q / half;
                int j  = q - g * half;
                int i0 = g * 2 * half + j;
                int i1 = i0 + half;
                float ar = ldsRe[col][i0], ai = ldsIm[col][i0];
                float br = ldsRe[col][i1], bi = ldsIm[col][i1];
                ldsRe[col][i0] = ar + br;
                ldsIm[col][i0] = ai + bi;
                float dr = ar - br, di = ai - bi;
                int k = j * (128 / half);
                float wr = twRe[k], wi = twIm[k];
                ldsRe[col][i1] = dr * wr - di * wi;
                ldsIm[col][i1] = dr * wi + di * wr;
            }
        }
        __syncthreads();
    }

    unsigned short* obase = Abf + (size_t)m * NX;
    #pragma unroll
    for (int it = 0; it < 16; ++it) {
        int li = it * 256 + tid;
        int ky = li >> 4;
        int cc = li & 15;
        int kx = k0 + cc;
        int rk = bitrev8(ky);
        float s = (((ky + kx) & 1) ? -1.0f : 1.0f) * (1.0f / 256.0f);
        unsigned pack = ((unsigned)f2bf(s * ldsIm[cc][rk]) << 16)
                      |  (unsigned)f2bf(s * ldsRe[cc][rk]);
        *(unsigned*)(obase + ((size_t)ky * NXS + kx) * 2) = pack;
    }
}

// ---------------------------------------------------------------------------
// VT -> fragment-ordered bf16 (k=(lane>>4)*8+j, f=lane&15, zero-padded).
// ---------------------------------------------------------------------------
__global__ __launch_bounds__(256) void vt_prep_kernel(
        const float* __restrict__ VT, unsigned short* __restrict__ VTfrag) {
    int i = blockIdx.x * 256 + threadIdx.x;
    if (i >= NFT * 512) return;
    int ft = i >> 9, r = i & 511, lane = r >> 3, j = r & 7;
    int k = (lane >> 4) * 8 + j;
    int f = ft * 16 + (lane & 15);
    unsigned short v = 0;
    if (k < NBASIS && f < NF) v = f2bf(VT[k * NF + f]);
    VTfrag[i] = v;
}

// ---------------------------------------------------------------------------
// Stage 3. R15 confirmed the in-order-vmcnt convoy theory (-66 us). This
// round removes the REMAINING self-inflicted serialization:
//  (1) no intra-loop wave_barrier/lgkmcnt(0)/sched_barrier — per-wave DS ops
//      to may-alias addresses execute in order in HW, and the compiler
//      preserves program order for may-alias LDS accesses, inserting only
//      counted data waits -> ft iterations can overlap (MFMA of ft+1 under
//      the drain of ft).
//  (2) Y staging software-pipelined: channel cc+1's 4 dwordx4 loads issue
//      BEFORE cc's NT-store stream (older loads retire before younger
//      stores -> zero store-queue drains anywhere in the kernel).
// ---------------------------------------------------------------------------
__global__ __launch_bounds__(256) void project_mfma_kernel(
        const unsigned short* __restrict__ Abf,    // [240][NX] bf16
        const unsigned short* __restrict__ VTfrag, // [13][64][8] bf16
        const void*           __restrict__ maskT,  // [200][NX] byte or int32
        float* __restrict__ out) {
    __shared__ __align__(16) unsigned char smem[4][4864];      // 19456 B
    __shared__ __align__(16) unsigned short vtlds[NFT * 512];  // 13312 B

    const int tid  = threadIdx.x;
    const int wv   = tid >> 6;
    const int lane = tid & 63;
    const int ksec = lane >> 4;
    const int fr   = lane & 15;
    const int c0   = blockIdx.y * CPB;
    const int n0w  = blockIdx.x * 256 + wv * 64;

    // Copy VTfrag to LDS (one block barrier, before any NT store).
    {
        const u32x4* src = (const u32x4*)VTfrag;
        u32x4*       dst = (u32x4*)vtlds;
        for (int i = tid; i < NFT * 512 / 8; i += 256) dst[i] = src[i];
    }

    // Detect mask storage: bool-as-byte vs int32 (uniform, scalar loads).
    const unsigned* mwd = (const unsigned*)maskT;
    bool byteMode = false;
    #pragma unroll
    for (int i = 0; i < 32; ++i) byteMode |= (mwd[i] > 1u);

    // Bit-pack this lane's mask: bit p = ft*16 + fn*4 + r  (f=ft*16+fr,
    // n = n0w + fn*16 + ksec*4 + r). All loads happen BEFORE any store.
    unsigned mbits[7] = {0u, 0u, 0u, 0u, 0u, 0u, 0u};
    if (byteMode) {
        const unsigned char* mb = (const unsigned char*)maskT + n0w + ksec * 4;
        #pragma unroll
        for (int ft = 0; ft < NFT; ++ft) {
            const int f_l = ft * 16 + fr;
            #pragma unroll
            for (int fn = 0; fn < 4; ++fn) {
                unsigned w = (f_l < NF)
                    ? *(const unsigned*)(mb + (size_t)f_l * NX + fn * 16) : 0u;
                unsigned nib = (w | (w >> 7) | (w >> 14) | (w >> 21)) & 0xFu;
                const int p = ft * 16 + fn * 4;
                mbits[p >> 5] |= nib << (p & 31);
            }
        }
    } else {
        const int* mi = (const int*)maskT + n0w + ksec * 4;
        #pragma unroll
        for (int ft = 0; ft < NFT; ++ft) {
            const int f_l = ft * 16 + fr;
            #pragma unroll
            for (int fn = 0; fn < 4; ++fn) {
                unsigned nib = 0u;
                if (f_l < NF) {
                    u32x4 v = *(const u32x4*)(mi + (size_t)f_l * NX + fn * 16);
                    nib = (v.x ? 1u : 0u) | (v.y ? 2u : 0u)
                        | (v.z ? 4u : 0u) | (v.w ? 8u : 0u);
                }
                const int p = ft * 16 + fn * 4;
                mbits[p >> 5] |= nib << (p & 31);
            }
        }
    }

    unsigned short (*ylds)[72] = (unsigned short (*)[72])smem[wv]; // 32x72 bf16
    float          (*ldsW)[68] = (float (*)[68])smem[wv];          // 16x68 f32

    // Prologue: load channel c0's Y strip into registers (before any store).
    const int yrow = (lane >> 3) * 4;            // helper decomposition below
    u32x4 ycur[4];
    {
        const unsigned short* src = Abf + (size_t)c0 * NBASIS * NX + n0w;
        #pragma unroll
        for (int i = 0; i < 4; ++i) {
            int idx = lane + 64 * i;             // 0..255
            int row = idx >> 3, seg = idx & 7;
            ycur[i] = (u32x4)(0u, 0u, 0u, 0u);
            if (row < NBASIS)
                ycur[i] = *(const u32x4*)(src + (size_t)row * NX + seg * 8);
        }
    }
    (void)yrow;

    __syncthreads();     // vtlds ready

    #pragma unroll 1
    for (int cc = 0; cc < CPB; ++cc) {
        const int c = c0 + cc;

        // Write staged Y regs to LDS (DS in-order; compiler keeps may-alias order).
        #pragma unroll
        for (int i = 0; i < 4; ++i) {
            int idx = lane + 64 * i;
            int row = idx >> 3, seg = idx & 7;
            *(u32x4*)&ylds[row][seg * 8] = ycur[i];
        }

        // Gather A-frags: yfrag[fn][j] = Y[k=ksec*8+j][n_local=fn*16+fr].
        bf16x8 yfrag[4];
        #pragma unroll
        for (int fn = 0; fn < 4; ++fn) {
            #pragma unroll
            for (int j = 0; j < 8; ++j)
                yfrag[fn][j] = (short)ylds[ksec * 8 + j][fn * 16 + fr];
        }

        // Issue next channel's Y loads BEFORE this channel's store stream.
        if (cc + 1 < CPB) {
            const unsigned short* src = Abf + (size_t)(c + 1) * NBASIS * NX + n0w;
            #pragma unroll
            for (int i = 0; i < 4; ++i) {
                int idx = lane + 64 * i;
                int row = idx >> 3, seg = idx & 7;
                u32x4 v = (u32x4)(0u, 0u, 0u, 0u);
                if (row < NBASIS)
                    v = *(const u32x4*)(src + (size_t)row * NX + seg * 8);
                ycur[i] = v;
            }
        }

        float* outc = out + (size_t)c * NF * NX;

        #pragma unroll
        for (int ft = 0; ft < NFT; ++ft) {
            bf16x8 vt = *(const bf16x8*)&vtlds[ft * 512 + lane * 8]; // lgkm only

            #pragma unroll
            for (int fn = 0; fn < 4; ++fn) {
                const int p = ft * 16 + fn * 4;
                const unsigned nib = (mbits[p >> 5] >> (p & 31)) & 0xFu;
                f32x4 d = __builtin_amdgcn_mfma_f32_16x16x32_bf16(
                    yfrag[fn], vt, (f32x4)(0.f, 0.f, 0.f, 0.f), 0, 0, 0);
                f32x4 o;
                #pragma unroll
                for (int r = 0; r < 4; ++r)
                    o[r] = (nib & (1u << r)) ? d[r] : 0.0f;
                *(f32x4*)&ldsW[fr][fn * 16 + ksec * 4] = o;
            }

            // f-major drain: per instr 4 f-rows x 256 B contiguous (1 KB).
            #pragma unroll
            for (int rl = 0; rl < 4; ++rl) {
                int f_local = rl * 4 + ksec;
                int f = ft * 16 + f_local;
                f32x4 v = *(const f32x4*)&ldsW[f_local][fr * 4];
                if (f < NF)
                    __builtin_nontemporal_store(v,
                        (f32x4*)(outc + (size_t)f * NX + n0w + fr * 4));
            }
        }
    }
}

extern "C" void kernel_launch(void* const* d_in, const int* in_sizes, int n_in,
                              void* d_out, int out_size, void* d_ws, size_t ws_size,
                              hipStream_t stream) {
    const float* x    = (const float*)d_in[0];   // (30,256,256,2) f32
    const float* csm  = (const float*)d_in[1];   // (8,256,256,2) f32
    const float* VT   = (const float*)d_in[2];   // (30,200) f32
    const void*  mask = d_in[3];                 // (200,131072) bool/int
    float* out = (float*)d_out;                  // (8,200,131072) f32

    char* ws = (char*)d_ws;
    unsigned short* Amid   = (unsigned short*)ws;                         // 62.9 MB
    unsigned short* Abf    = (unsigned short*)(ws + ((size_t)64 << 20));  // 62.9 MB
    unsigned short* VTfrag = (unsigned short*)(ws + ((size_t)128 << 20)); // 13.3 KB

    vt_prep_kernel<<<(NFT * 512 + 255) / 256, 256, 0, stream>>>(VT, VTfrag);
    fft_rows_kernel<<<NIMG * 64, 256, 0, stream>>>(x, csm, Amid);
    fft_cols_kernel<<<NIMG * 16, 256, 0, stream>>>(Amid, Abf);
    project_mfma_kernel<<<dim3(NX / 256, NCH / CPB), 256, 0, stream>>>(
        Abf, VTfrag, mask, out);
}